// Round 9
// baseline (370.003 us; speedup 1.0000x reference)
//
#include <hip/hip_runtime.h>
#include <math.h>

#define B_ 4
#define N_ 2048
#define M_ 1024
#define K_ 32
#define HEADS_ 4
#define NH_ 128
#define PI_F 3.14159265358979323846f

typedef unsigned long long ull;
typedef __attribute__((ext_vector_type(8))) _Float16 half8;
typedef __attribute__((ext_vector_type(4))) _Float16 half4v;
typedef __attribute__((ext_vector_type(2))) _Float16 half2v;
typedef __attribute__((ext_vector_type(4))) float f32x4;

// workspace offsets (in floats)
#define OFF_WGW   0          // 16384
#define OFF_CB    16384      // 128
#define OFF_CGV   16512      // 128
#define OFF_WVOTH 16640      // 12*128 halfs = 768 floats
#define OFF_OUTC  17408      // 4
#define OFF_KB    17412      // 16384
#define OFF_BASEH 33796      // B*M*128 halfs = 262144 floats
#define OFF_W2F   295940     // 40960 halfs = 20480 floats
#define OFF_WV1F  316420     // 16384 halfs = 8192 floats
#define OFF_U     324612     // 33280
#define OFF_E     357892     // 256
#define OFF_WQK   358148     // 128*524 = 67072 (fp32)
#define OFF_KWCC  425220     // 524
#define OFF_KWH   425744     // B*M*4*136 halfs = 1114112 floats
#define OFF_VFH   1539856    // B*M*128 halfs = 262144 floats
#define OFF_BAR   1802000    // 2 ints
// total = 1802002 floats (~7.2 MB)

// W2f/wv1f fragment index for (k, n): [mt][ks][lane][i]
__device__ __forceinline__ int w2f_idx(int k, int n, int nks) {
  int mt = n >> 4, ks = k >> 5;
  int lane = (((k >> 3) & 3) << 4) | (n & 15);
  return (((mt*nks + ks)*64 + lane) << 3) + (k & 7);
}

__device__ __forceinline__ void grid_barrier(int* cnt, int nblocks) {
  __syncthreads();
  if (threadIdx.x == 0) {
    __threadfence();                 // release: make this block's stores visible
    atomicAdd(cnt, 1);
    while (__hip_atomic_load(cnt, __ATOMIC_RELAXED, __HIP_MEMORY_SCOPE_AGENT) < nblocks) {
      __builtin_amdgcn_s_sleep(2);
    }
  }
  __syncthreads();
  __threadfence();                   // acquire: invalidate caches before consuming
}

// ---------- fused precompute + latent: grid MUST be 256 blocks ----------
__global__ __launch_bounds__(256) void enf_pre(
    const float* __restrict__ w3v, const float* __restrict__ wv1,
    const float* __restrict__ w2q, const float* __restrict__ w3q,
    const float* __restrict__ b2q, const float* __restrict__ b3q,
    const float* __restrict__ w2v, const float* __restrict__ wk,
    const float* __restrict__ bk, const float* __restrict__ b2v,
    const float* __restrict__ b3v, const float* __restrict__ bv1,
    const float* __restrict__ wv2, const float* __restrict__ wout,
    const float* __restrict__ bv2, const float* __restrict__ bout,
    const float* __restrict__ c, const float* __restrict__ wvw,
    const float* __restrict__ bv,
    float* __restrict__ WGW, float* __restrict__ U, float* __restrict__ E,
    _Float16* __restrict__ wv1f,
    _Float16* __restrict__ W2f, float* __restrict__ cb, float* __restrict__ cgv,
    _Float16* __restrict__ wvoT_h, float* __restrict__ outconst,
    float* __restrict__ WQK, float* __restrict__ kwcc,
    _Float16* __restrict__ kwh, float* __restrict__ kb,
    _Float16* __restrict__ vfh, _Float16* __restrict__ baseh,
    int* __restrict__ barcnt) {
  const int blk = blockIdx.x, tid = threadIdx.x;
  __shared__ float cls[16][128];
  __shared__ float evs[16][128];

  // ======== stage 1: WGW | U | E | wv1f ========
  if (blk < 64) {
    int o = blk*256 + tid;
    int i = o >> 7, j = o & 127;
    float acc = 0.f;
    for (int r = 0; r < 128; ++r) acc = fmaf(w3v[i*256 + 128 + r], wv1[r*128 + j], acc);
    WGW[o] = acc;
  } else if (blk < 194) {
    int a = blk - 64, s = tid;
    float acc = 0.f;
    for (int i = 0; i < 128; ++i) acc = fmaf(w2q[a*128 + i], w3q[i*256 + s], acc);
    U[a*256 + s] = acc;
  } else if (blk == 194) {
    int s = tid;
    float acc = b3q[s];
    for (int j = 0; j < 128; ++j) acc = fmaf(b2q[j], w3q[j*256 + s], acc);
    E[s] = acc;
  } else {                   // wv1f frags: [mt8][ks4][lane64][i8]
    for (int idx = (blk - 195)*256 + tid; idx < 16384; idx += 61*256) {
      int i = idx & 7, lane = (idx >> 3) & 63;
      int rest = idx >> 9;
      int ks = rest & 3, mt = rest >> 2;
      int k = ks*32 + ((lane >> 4) << 3) + i;
      int j = mt*16 + (lane & 15);
      wv1f[idx] = (_Float16)wv1[k*128 + j];
    }
  }
  grid_barrier(barcnt + 0, 256);

  // ======== stage 2: W2f | consts+pad | WQK | kwcc ========
  if (blk < 130) {           // W2 row -> fragment scatter (fp16)
    int a = blk, j = tid;
    float acc = 0.f;
    if (j < 128) {
      for (int i = 0; i < 128; ++i) acc = fmaf(w2v[a*128 + i], w3v[i*256 + j], acc);
    } else {
      int j2 = j - 128;
      for (int i = 0; i < 128; ++i) acc = fmaf(w2v[a*128 + i], WGW[i*128 + j2], acc);
    }
    W2f[w2f_idx(a, j, 5)] = (_Float16)acc;
  } else if (blk == 130) {   // consts + W2f zero-pad k in [130,160)
    if (tid < 128) {
      float a1 = 0.f;
      for (int i = 0; i < 128; ++i) a1 = fmaf(b2v[i], w3v[i*256 + tid], a1);
      cb[tid] = a1 + b3v[tid];
      float a2 = 0.f;
      for (int i = 0; i < 128; ++i) a2 = fmaf(b2v[i], WGW[i*128 + tid], a2);
      for (int r = 0; r < 128; ++r) a2 = fmaf(b3v[128 + r], wv1[r*128 + tid], a2);
      cgv[tid] = a2 + bv1[tid];
    }
    for (int o = tid; o < 1536; o += 256) {
      int r12 = o >> 7, i = o & 127;
      int h = r12 / 3, cc = r12 - h*3;
      float acc = 0.f;
      for (int k = 0; k < 128; ++k)
        acc = fmaf(wv2[i*512 + h*128 + k], wout[(h*128 + k)*3 + cc], acc);
      wvoT_h[r12*128 + i] = (_Float16)acc;
    }
    for (int o = tid; o < 7680; o += 256) {
      int k = 130 + (o >> 8), n = o & 255;
      W2f[w2f_idx(k, n, 5)] = (_Float16)0.f;
    }
    if (tid < 3) {
      float acc = bout[tid];
      for (int r = 0; r < 512; ++r) acc = fmaf(bv2[r], wout[r*3 + tid], acc);
      outconst[tid] = acc;
    }
  } else if (blk == 255) {   // kwcc
    for (int col = tid; col < 524; col += 256) {
      float acc = 0.f;
      if (col < 520) {
        int h = col / 130, a = col - h*130;
        const float* ur = U + a*256 + h*64;
        const float* br = bk + h*64;
        for (int q = 0; q < 64; ++q) acc = fmaf(ur[q], br[q], acc);
      } else {
        int h = col - 520;
        const float* er = E + h*64;
        const float* br = bk + h*64;
        for (int q = 0; q < 64; ++q) acc = fmaf(er[q], br[q], acc);
      }
      kwcc[col] = acc;
    }
  } else {                   // WQK rows, blocks 131..254 cover l = 0..127
    for (int l = blk - 131; l < 128; l += 124) {
      for (int col = tid; col < 524; col += 256) {
        float acc = 0.f;
        if (col < 520) {
          int h = col / 130, a = col - h*130;
          const float* ur = U + a*256 + h*64;
          const float* wr = wk + l*256 + h*64;
          for (int q = 0; q < 64; ++q) acc = fmaf(ur[q], wr[q], acc);
        } else {
          int h = col - 520;
          const float* er = E + h*64;
          const float* wr = wk + l*256 + h*64;
          for (int q = 0; q < 64; ++q) acc = fmaf(er[q], wr[q], acc);
        }
        WQK[l*524 + col] = acc;
      }
    }
  }
  grid_barrier(barcnt + 1, 256);

  // ======== stage 3: latent tables, 16 latents per block ========
  {
    const int bm0 = blk * 16;
    for (int t = tid; t < 2048; t += 256) cls[t >> 7][t & 127] = c[(size_t)bm0*128 + t];
    __syncthreads();
    for (int col = tid; col < 652; col += 256) {
      float a[16];
#pragma unroll
      for (int i = 0; i < 16; ++i) a[i] = 0.f;
      if (col < 128) {
        for (int l = 0; l < 128; ++l) {
          float w = wvw[l*128 + col];
#pragma unroll
          for (int i = 0; i < 16; ++i) a[i] = fmaf(cls[i][l], w, a[i]);
        }
        float bvc = bv[col];
        float cbf = 1.f + cb[col];
#pragma unroll
        for (int i = 0; i < 16; ++i) {
          float v = a[i] + bvc;
          vfh[(size_t)(bm0 + i)*128 + col] = (_Float16)v;
          evs[i][col] = v*cbf;
        }
      } else {
        const float* wq = WQK + (col - 128);
        for (int l = 0; l < 128; ++l) {
          float w = wq[l*524];
#pragma unroll
          for (int i = 0; i < 16; ++i) a[i] = fmaf(cls[i][l], w, a[i]);
        }
        float cc = kwcc[col - 128];
        if (col < 648) {
          int h = (col - 128) / 130, aa = (col - 128) - h*130;
#pragma unroll
          for (int i = 0; i < 16; ++i)
            kwh[((size_t)(bm0 + i)*4 + h)*136 + aa] = (_Float16)(a[i] + cc);
        } else {
          int h = col - 648;
#pragma unroll
          for (int i = 0; i < 16; ++i)
            kb[(size_t)(bm0 + i)*4 + h] = a[i] + cc;
        }
      }
    }
    __syncthreads();
    {
      const int col = tid & 127, i0 = (tid >> 7) * 8;
      float bacc[8];
#pragma unroll
      for (int i = 0; i < 8; ++i) bacc[i] = 0.f;
      for (int l = 0; l < 128; ++l) {
        float w = wv1[l*128 + col];
#pragma unroll
        for (int i = 0; i < 8; ++i) bacc[i] = fmaf(evs[i0 + i][l], w, bacc[i]);
      }
#pragma unroll
      for (int i = 0; i < 8; ++i)
        baseh[(size_t)(bm0 + i0 + i)*128 + col] = (_Float16)bacc[i];
    }
  }
}

// sfv B-fragment position: [nt(2)][ks(5)][lane(64)][i(8)] halfs
__device__ __forceinline__ int fragpos(int k, int e) {
  return ((((e >> 4)*5 + (k >> 5))*64 + (((k >> 3) & 3) << 4) + (e & 15)) << 3) + (k & 7);
}

// ---------- main kernel: one block per (b,n), batch->XCD swizzled ----------
__global__ __launch_bounds__(256, 8) void enf_main(
    const float* __restrict__ x, const float* __restrict__ p,
    const float* __restrict__ g,
    const float* __restrict__ w1q, const float* __restrict__ w1v,
    const _Float16* __restrict__ w2f, const _Float16* __restrict__ wv1f,
    const float* __restrict__ cgv, const _Float16* __restrict__ wvoT_h,
    const float* __restrict__ outconst,
    const _Float16* __restrict__ kwh, const float* __restrict__ kb,
    const _Float16* __restrict__ vfh, const _Float16* __restrict__ baseh,
    float* __restrict__ out) {
  // batch->XCD affinity: XCD = wgid%8 serves exactly one batch (b = (bid&7)>>1)
  const int bid = blockIdx.x;
  const int bn = (((bid & 7) >> 1) << 11) | ((bid & 1) << 10) | (bid >> 3);
  const int b = bn >> 11;          // N = 2048
  const int tid = threadIdx.x;
  const int lane = tid & 63;
  const int wid = tid >> 6;

  __shared__ alignas(16) float S[4640];
  __shared__ int   selm[K_];
  __shared__ float seld[K_];
  __shared__ float gkv[K_];
  __shared__ float bi0[K_], bi1[K_];
  __shared__ float logits_s[K_*HEADS_];
  __shared__ float hpart[HEADS_*4];

  float* candd = S;
  int*   candm = (int*)(S + 128);
  half2v* sfq2 = (half2v*)S;                 // [65][32] half2 words
  _Float16* sfvB = (_Float16*)(S + 2080);    // 5120 halfs
  _Float16* evlds = (_Float16*)S;            // [32][136]
  _Float16* gt_h  = (_Float16*)S + 4352;     // [32][136]
  float* poL   = S;                          // [32][12]

  const float x0 = x[bn*2 + 0];
  const float x1 = x[bn*2 + 1];
  const float2* pb2 = (const float2*)(p + (size_t)b*M_*2);

  // ---- Phase A: per-wave top-32 via binary-search threshold on float bits ----
  unsigned db[4]; int mm[4];
#pragma unroll
  for (int s = 0; s < 4; ++s) {
    int m = wid*256 + s*64 + lane;
    float2 pv = pb2[m];
    float d0 = x0 - pv.x, d1 = x1 - pv.y;
    float d = __fadd_rn(__fmul_rn(d0, d0), __fmul_rn(d1, d1));
    db[s] = __float_as_uint(d);
    mm[s] = m;
  }
  unsigned xth = 0;
  for (int bit = 30; bit >= 0; --bit) {
    unsigned trial = xth | (1u << bit);
    int cnt = __popcll(__ballot(db[0] < trial)) + __popcll(__ballot(db[1] < trial))
            + __popcll(__ballot(db[2] < trial)) + __popcll(__ballot(db[3] < trial));
    if (cnt < 32) xth = trial;
  }
  {
    ull bl[4], be[4];
#pragma unroll
    for (int s = 0; s < 4; ++s) {
      bl[s] = __ballot(db[s] < xth);
      be[s] = __ballot(db[s] == xth);
    }
    int r = __popcll(bl[0]) + __popcll(bl[1]) + __popcll(bl[2]) + __popcll(bl[3]);
    const ull lmask = (1ull << lane) - 1ull;
    int pl = 0, pe = 0;
#pragma unroll
    for (int s = 0; s < 4; ++s) {
      if (db[s] < xth) {
        int pos = pl + __popcll(bl[s] & lmask);
        candd[wid*K_ + pos] = __uint_as_float(db[s]);
        candm[wid*K_ + pos] = mm[s];
      } else if (db[s] == xth) {
        int pos = r + pe + __popcll(be[s] & lmask);
        if (pos < K_) {
          candd[wid*K_ + pos] = __uint_as_float(db[s]);
          candm[wid*K_ + pos] = mm[s];
        }
      }
      pl += __popcll(bl[s]);
      pe += __popcll(be[s]);
    }
  }
  __syncthreads();
  // merge: rank + fill selm/seld/gkv/bi in one pass
  if (tid < 128) {
    float d = candd[tid];
    int m = candm[tid];
    int rank = 0;
    for (int i = 0; i < 128; ++i) {
      float di = candd[i];
      rank += (di < d || (di == d && i < tid)) ? 1 : 0;
    }
    if (rank < K_) {
      selm[rank] = m; seld[rank] = d;
      gkv[rank] = g[(size_t)b*M_ + m];
      float2 pv = pb2[m];
      bi0[rank] = x0 - pv.x;
      bi1[rank] = x1 - pv.y;
    }
  }
  __syncthreads();

  // ---- Phase B: sin features, sfq fp16 half2 words, sfv fp16 B-frags ----
  if (tid < 32) {
    const int e = tid;
    half2v h;
    h[0] = (_Float16)__sinf(bi0[e]);
    h[1] = (_Float16)__sinf(bi1[e]);
    sfq2[e] = h;                      // word 0: k=0,1
    sfvB[fragpos(0, e)] = h[0];
    sfvB[fragpos(1, e)] = h[1];
  }
  for (int t = tid; t < 960; t += 256) {      // zero-pad sfv frags k=130..159
    int k = 130 + (t >> 5), e = t & 31;
    sfvB[fragpos(k, e)] = (_Float16)0.f;
  }
  {
    const int e = tid & 31;
    const int jg = tid >> 5;           // 0..7
    const float s0 = PI_F*(bi0[e] + 1.f), s1 = PI_F*(bi1[e] + 1.f);
#pragma unroll
    for (int t4 = 0; t4 < 4; ++t4) {
      const int J = 2*jg + 16*t4;      // even, covers 0..62
      float eqa = s0*w1q[J]     + s1*w1q[64 + J];
      float eqb = s0*w1q[J + 1] + s1*w1q[64 + J + 1];
      float eva = s0*w1v[J]     + s1*w1v[64 + J];
      float evb = s0*w1v[J + 1] + s1*w1v[64 + J + 1];
      half2v hs, hc;
      hs[0] = (_Float16)__sinf(eqa); hs[1] = (_Float16)__sinf(eqb);
      hc[0] = (_Float16)__cosf(eqa); hc[1] = (_Float16)__cosf(eqb);
      sfq2[(1 + (J >> 1))*32 + e]  = hs;   // k = 2+J, 3+J
      sfq2[(33 + (J >> 1))*32 + e] = hc;   // k = 66+J, 67+J
      sfvB[fragpos(2 + J, e)]  = (_Float16)__sinf(eva);
      sfvB[fragpos(3 + J, e)]  = (_Float16)__sinf(evb);
      sfvB[fragpos(66 + J, e)] = (_Float16)__cosf(eva);
      sfvB[fragpos(67 + J, e)] = (_Float16)__cosf(evb);
    }
  }
  __syncthreads();

  // ---- Phase C: attention logits via v_dot2_f32_f16 (waves 0,1) ----
  if (tid < 128) {
    const int e = tid >> 2, h = tid & 3;
    const int m = selm[e];
    const _Float16* kwrow = kwh + ((size_t)((b*M_ + m)*4 + h))*136;
    float accq = kb[(size_t)(b*M_ + m)*4 + h];
    const half8* kw8 = (const half8*)kwrow;
    const half2v* sq = sfq2 + e;
#pragma unroll 4
    for (int q8 = 0; q8 < 16; ++q8) {
      half8 kv = kw8[q8];
      half2v k0; k0[0] = kv[0]; k0[1] = kv[1];
      half2v k1; k1[0] = kv[2]; k1[1] = kv[3];
      half2v k2; k2[0] = kv[4]; k2[1] = kv[5];
      half2v k3; k3[0] = kv[6]; k3[1] = kv[7];
      accq = __builtin_amdgcn_fdot2(sq[(4*q8 + 0)*32], k0, accq, false);
      accq = __builtin_amdgcn_fdot2(sq[(4*q8 + 1)*32], k1, accq, false);
      accq = __builtin_amdgcn_fdot2(sq[(4*q8 + 2)*32], k2, accq, false);
      accq = __builtin_amdgcn_fdot2(sq[(4*q8 + 3)*32], k3, accq, false);
    }
    {
      half2v kt = *(const half2v*)(kwrow + 128);
      accq = __builtin_amdgcn_fdot2(sq[64*32], kt, accq, false);
    }
    const float gk = gkv[e];
    logits_s[tid] = accq - seld[e]/(gk*gk);
  }

  // ---- GEMM1 (MFMA): C1T = W2^T @ sfv^T
  f32x4 acc1[4][2];
#pragma unroll
  for (int mi = 0; mi < 4; ++mi)
#pragma unroll
    for (int nt = 0; nt < 2; ++nt) acc1[mi][nt] = (f32x4)0.f;
  {
    const half8* w2f8  = (const half8*)w2f;
    const half8* sfvB8 = (const half8*)sfvB;
#pragma unroll
    for (int ks = 0; ks < 5; ++ks) {
      half8 bf0 = sfvB8[(0*5 + ks)*64 + lane];
      half8 bf1 = sfvB8[(1*5 + ks)*64 + lane];
#pragma unroll
      for (int mi = 0; mi < 4; ++mi) {
        const int mt = (mi < 2) ? (2*wid + mi) : (8 + 2*wid + (mi - 2));
        half8 af = w2f8[(mt*5 + ks)*64 + lane];
        acc1[mi][0] = __builtin_amdgcn_mfma_f32_16x16x32_f16(af, bf0, acc1[mi][0], 0, 0, 0);
        acc1[mi][1] = __builtin_amdgcn_mfma_f32_16x16x32_f16(af, bf1, acc1[mi][1], 0, 0, 0);
      }
    }
  }
  __syncthreads();   // sfq + sfvB dead

  // ---- epilogue: evec (mi 0,1) -> evlds fp16; gterm (mi 2,3) -> registers ----
  f32x4 tg[2][2];
#pragma unroll
  for (int mi = 0; mi < 2; ++mi) {
    const int j0 = (2*wid + mi)*16 + ((lane >> 4) << 2);
#pragma unroll
    for (int nt = 0; nt < 2; ++nt) {
      const int e = nt*16 + (lane & 15);
      const half4v v4 = *(const half4v*)(vfh + ((size_t)(b*M_ + selm[e]))*NH_ + j0);
      f32x4 a = acc1[mi][nt];
      half4v hv;
      hv[0] = (_Float16)((float)v4[0] * a[0]);
      hv[1] = (_Float16)((float)v4[1] * a[1]);
      hv[2] = (_Float16)((float)v4[2] * a[2]);
      hv[3] = (_Float16)((float)v4[3] * a[3]);
      *(half4v*)(evlds + e*136 + j0) = hv;
    }
  }
#pragma unroll
  for (int mi = 0; mi < 2; ++mi) {
    const int j0 = 32*wid + mi*16 + ((lane >> 4) << 2);
    const float4 c4 = *(const float4*)(cgv + j0);
#pragma unroll
    for (int nt = 0; nt < 2; ++nt) {
      const int e = nt*16 + (lane & 15);
      const half4v b4 = *(const half4v*)(baseh + ((size_t)(b*M_ + selm[e]))*NH_ + j0);
      f32x4 a = acc1[2 + mi][nt];
      tg[mi][nt][0] = a[0] + (float)b4[0] + c4.x;
      tg[mi][nt][1] = a[1] + (float)b4[1] + c4.y;
      tg[mi][nt][2] = a[2] + (float)b4[2] + c4.z;
      tg[mi][nt][3] = a[3] + (float)b4[3] + c4.w;
    }
  }
  __syncthreads();

  // ---- GEMM2 (MFMA): acc = tg + wv1^T @ ev^T ----
  {
    const half8* wv1f8 = (const half8*)wv1f;
    const half8* evB   = (const half8*)evlds;   // index: e*17 + ks*4 + (lane>>4)
#pragma unroll
    for (int ks = 0; ks < 4; ++ks) {
      half8 bf0 = evB[(lane & 15)*17 + ks*4 + (lane >> 4)];
      half8 bf1 = evB[(16 + (lane & 15))*17 + ks*4 + (lane >> 4)];
#pragma unroll
      for (int mi = 0; mi < 2; ++mi) {
        half8 af = wv1f8[((2*wid + mi)*4 + ks)*64 + lane];
        tg[mi][0] = __builtin_amdgcn_mfma_f32_16x16x32_f16(af, bf0, tg[mi][0], 0, 0, 0);
        tg[mi][1] = __builtin_amdgcn_mfma_f32_16x16x32_f16(af, bf1, tg[mi][1], 0, 0, 0);
      }
    }
  }
  // gelu epilogue -> gt fp16 (disjoint from evlds; no barrier needed)
#pragma unroll
  for (int mi = 0; mi < 2; ++mi) {
    const int j0 = (2*wid + mi)*16 + ((lane >> 4) << 2);
#pragma unroll
    for (int nt = 0; nt < 2; ++nt) {
      const int e = nt*16 + (lane & 15);
      f32x4 a = tg[mi][nt];
      half4v gv;
#pragma unroll
      for (int jj = 0; jj < 4; ++jj) {
        float tval = a[jj];
        float u = 0.79788456080286536f*(tval + 0.044715f*tval*tval*tval);
        float ex = __expf(2.f*u);
        float th = 1.f - 2.f/(ex + 1.f);
        gv[jj] = (_Float16)(0.5f*tval*(1.f + th));
      }
      *(half4v*)(gt_h + e*136 + j0) = gv;
    }
  }
  __syncthreads();

  // ---- Phase F: po[e][12] = gt[e] @ wvoT^T via v_dot2_f32_f16 ----
  for (int t = tid; t < K_*12; t += 256) {
    const int e = t / 12, r = t - (t/12)*12;
    const half8* wr8 = (const half8*)(wvoT_h + r*NH_);
    const half8* gr8 = (const half8*)(gt_h + e*136);
    float a0 = 0.f, a1 = 0.f, a2 = 0.f, a3 = 0.f;
#pragma unroll 4
    for (int q = 0; q < 16; ++q) {
      half8 gq = gr8[q];
      half8 wq = wr8[q];
      half2v g0; g0[0] = gq[0]; g0[1] = gq[1];
      half2v g1; g1[0] = gq[2]; g1[1] = gq[3];
      half2v g2; g2[0] = gq[4]; g2[1] = gq[5];
      half2v g3; g3[0] = gq[6]; g3[1] = gq[7];
      half2v w0; w0[0] = wq[0]; w0[1] = wq[1];
      half2v w1; w1[0] = wq[2]; w1[1] = wq[3];
      half2v w2; w2[0] = wq[4]; w2[1] = wq[5];
      half2v w3; w3[0] = wq[6]; w3[1] = wq[7];
      a0 = __builtin_amdgcn_fdot2(g0, w0, a0, false);
      a1 = __builtin_amdgcn_fdot2(g1, w1, a1, false);
      a2 = __builtin_amdgcn_fdot2(g2, w2, a2, false);
      a3 = __builtin_amdgcn_fdot2(g3, w3, a3, false);
    }
    poL[t] = (a0 + a1) + (a2 + a3);
  }
  __syncthreads();

  // ---- Phase G: softmax over K per head + combine ----
  if (tid < 128) {
    const int h = tid >> 5, e = tid & 31;
    float l = logits_s[e*4 + h];
    float mx = l;
#pragma unroll
    for (int off = 1; off < 32; off <<= 1) mx = fmaxf(mx, __shfl_xor(mx, off));
    float w = __expf(l - mx);
    float s = w;
#pragma unroll
    for (int off = 1; off < 32; off <<= 1) s += __shfl_xor(s, off);
    float att = w / s;
    float p0 = att * poL[e*12 + h*3 + 0];
    float p1 = att * poL[e*12 + h*3 + 1];
    float p2 = att * poL[e*12 + h*3 + 2];
#pragma unroll
    for (int off = 1; off < 32; off <<= 1) {
      p0 += __shfl_xor(p0, off);
      p1 += __shfl_xor(p1, off);
      p2 += __shfl_xor(p2, off);
    }
    if (e == 0) { hpart[h*4 + 0] = p0; hpart[h*4 + 1] = p1; hpart[h*4 + 2] = p2; }
  }
  __syncthreads();
  if (tid < 3) {
    out[(size_t)bn*3 + tid] = outconst[tid]
        + hpart[0*4 + tid] + hpart[1*4 + tid] + hpart[2*4 + tid] + hpart[3*4 + tid];
  }
}

extern "C" void kernel_launch(void* const* d_in, const int* in_sizes, int n_in,
                              void* d_out, int out_size, void* d_ws, size_t ws_size,
                              hipStream_t stream) {
  (void)in_sizes; (void)n_in; (void)out_size; (void)ws_size;
  const float* x    = (const float*)d_in[0];
  const float* p    = (const float*)d_in[1];
  const float* c    = (const float*)d_in[2];
  const float* g    = (const float*)d_in[3];
  const float* w1q  = (const float*)d_in[4];
  const float* w2q  = (const float*)d_in[5];
  const float* b2q  = (const float*)d_in[6];
  const float* w3q  = (const float*)d_in[7];
  const float* b3q  = (const float*)d_in[8];
  const float* w1v  = (const float*)d_in[9];
  const float* w2v  = (const float*)d_in[10];
  const float* b2v  = (const float*)d_in[11];
  const float* w3v  = (const float*)d_in[12];
  const float* b3v  = (const float*)d_in[13];
  const float* wk   = (const float*)d_in[14];
  const float* bk   = (const float*)d_in[15];
  const float* wvw  = (const float*)d_in[16];
  const float* bv   = (const float*)d_in[17];
  const float* wv1  = (const float*)d_in[18];
  const float* bv1  = (const float*)d_in[19];
  const float* wv2  = (const float*)d_in[20];
  const float* bv2  = (const float*)d_in[21];
  const float* wout = (const float*)d_in[22];
  const float* bout = (const float*)d_in[23];
  float* ws = (float*)d_ws;
  float* outp = (float*)d_out;

  hipMemsetAsync(ws + OFF_BAR, 0, 2*sizeof(int), stream);
  hipLaunchKernelGGL(enf_pre, dim3(256), dim3(256), 0, stream,
                     w3v, wv1, w2q, w3q, b2q, b3q, w2v, wk, bk, b2v, b3v, bv1,
                     wv2, wout, bv2, bout, c, wvw, bv,
                     ws + OFF_WGW, ws + OFF_U, ws + OFF_E,
                     (_Float16*)(ws + OFF_WV1F),
                     (_Float16*)(ws + OFF_W2F), ws + OFF_CB, ws + OFF_CGV,
                     (_Float16*)(ws + OFF_WVOTH), ws + OFF_OUTC,
                     ws + OFF_WQK, ws + OFF_KWCC,
                     (_Float16*)(ws + OFF_KWH), ws + OFF_KB,
                     (_Float16*)(ws + OFF_VFH), (_Float16*)(ws + OFF_BASEH),
                     (int*)(ws + OFF_BAR));
  hipLaunchKernelGGL(enf_main, dim3(B_*N_), dim3(256), 0, stream,
                     x, p, g, w1q, w1v,
                     (const _Float16*)(ws + OFF_W2F), (const _Float16*)(ws + OFF_WV1F),
                     ws + OFF_CGV, (const _Float16*)(ws + OFF_WVOTH), ws + OFF_OUTC,
                     (const _Float16*)(ws + OFF_KWH), ws + OFF_KB,
                     (const _Float16*)(ws + OFF_VFH), (const _Float16*)(ws + OFF_BASEH),
                     outp);
}

// Round 10
// 272.896 us; speedup vs baseline: 1.3558x; 1.3558x over previous
//
#include <hip/hip_runtime.h>
#include <math.h>

#define B_ 4
#define N_ 2048
#define M_ 1024
#define K_ 32
#define HEADS_ 4
#define NH_ 128
#define PI_F 3.14159265358979323846f

typedef unsigned long long ull;
typedef __attribute__((ext_vector_type(8))) _Float16 half8;
typedef __attribute__((ext_vector_type(4))) _Float16 half4v;
typedef __attribute__((ext_vector_type(2))) _Float16 half2v;
typedef __attribute__((ext_vector_type(4))) float f32x4;

// workspace offsets (in floats)
#define OFF_CB     0         // 128
#define OFF_CGV    128       // 128
#define OFF_WVOTH  256       // 768 (12*128 halfs)
#define OFF_OUTC   1024      // 4
#define OFF_BW     1028      // 128
#define OFF_E      1156      // 256
#define OFF_KB     1412      // 16384
#define OFF_U      17796     // 33280
#define OFF_W2A    51076     // 33280
#define OFF_W2F    84356     // 20480 (40960 halfs)
#define OFF_WV1F   104836    // 8192 (16384 halfs)
#define OFF_BASEH  113028    // 262144 (B*M*128 halfs)
#define OFF_KWH    375172    // 1114112 (B*M*4*136 halfs)
#define OFF_VFH    1489284   // 262144 (B*M*128 halfs)
// total = 1751428 floats (~7.0 MB)

// W2f/wv1f fragment index for (k, n): [mt][ks][lane][i]
__device__ __forceinline__ int w2f_idx(int k, int n, int nks) {
  int mt = n >> 4, ks = k >> 5;
  int lane = (((k >> 3) & 3) << 4) | (n & 15);
  return (((mt*nks + ks)*64 + lane) << 3) + (k & 7);
}

// ---------- preA: U | E+cb+bW | W2A | wv1f  (no internal deps) ----------
__global__ __launch_bounds__(256) void enf_preA(
    const float* __restrict__ w2q, const float* __restrict__ w3q,
    const float* __restrict__ b2q, const float* __restrict__ b3q,
    const float* __restrict__ w2v, const float* __restrict__ w3v,
    const float* __restrict__ b2v, const float* __restrict__ b3v,
    const float* __restrict__ wv1,
    float* __restrict__ U, float* __restrict__ E, float* __restrict__ cb,
    float* __restrict__ bW, float* __restrict__ W2A,
    _Float16* __restrict__ wv1f) {
  const int blk = blockIdx.x, tid = threadIdx.x;
  if (blk < 130) {               // U[a][s] = w2q @ w3q
    int a = blk, s = tid;
    float acc = 0.f;
    for (int i = 0; i < 128; ++i) acc = fmaf(w2q[a*128 + i], w3q[i*256 + s], acc);
    U[a*256 + s] = acc;
  } else if (blk == 130) {       // E | cb | bW
    int s = tid;
    float acc = b3q[s];
    for (int j = 0; j < 128; ++j) acc = fmaf(b2q[j], w3q[j*256 + s], acc);
    E[s] = acc;
    if (tid < 128) {
      float a1 = 0.f, a2 = 0.f;
      for (int i = 0; i < 128; ++i) {
        a1 = fmaf(b2v[i], w3v[i*256 + tid], a1);
        a2 = fmaf(b2v[i], w3v[i*256 + 128 + tid], a2);
      }
      cb[tid] = a1 + b3v[tid];
      bW[tid] = a2;
    }
  } else if (blk < 261) {        // W2A[a][j] = w2v @ w3v (both halves)
    int a = blk - 131, j = tid;
    float acc = 0.f;
    for (int i = 0; i < 128; ++i) acc = fmaf(w2v[a*128 + i], w3v[i*256 + j], acc);
    W2A[a*256 + j] = acc;
  } else {                       // wv1f frags: [mt8][ks4][lane64][i8], blocks 261..324
    int idx = (blk - 261)*256 + tid;
    int i = idx & 7, lane = (idx >> 3) & 63;
    int rest = idx >> 9;
    int ks = rest & 3, mt = rest >> 2;
    int k = ks*32 + ((lane >> 4) << 3) + i;
    int j = mt*16 + (lane & 15);
    wv1f[idx] = (_Float16)wv1[k*128 + j];
  }
}

// ---------- preBL: latent tables (256 blk) | W2f (130 blk) | consts (1 blk) ----------
__global__ __launch_bounds__(256) void enf_preBL(
    const float* __restrict__ c, const float* __restrict__ wk,
    const float* __restrict__ bk, const float* __restrict__ wvw,
    const float* __restrict__ bv, const float* __restrict__ wv1,
    const float* __restrict__ U, const float* __restrict__ E,
    const float* __restrict__ cb, const float* __restrict__ bW,
    const float* __restrict__ W2A, const float* __restrict__ b3v,
    const float* __restrict__ bv1, const float* __restrict__ wv2,
    const float* __restrict__ wout, const float* __restrict__ bv2,
    const float* __restrict__ bout,
    _Float16* __restrict__ W2f, float* __restrict__ cgv,
    _Float16* __restrict__ wvoT_h, float* __restrict__ outconst,
    _Float16* __restrict__ kwh, float* __restrict__ kb,
    _Float16* __restrict__ vfh, _Float16* __restrict__ baseh) {
  const int blk = blockIdx.x, tid = threadIdx.x;
  __shared__ float cls[16][128];
  __shared__ float kfl[16][256];
  __shared__ float evs[16][128];
  if (blk < 256) {
    // ---- latent: 16 latents per block ----
    const int bm0 = blk * 16;
    for (int t = tid; t < 2048; t += 256) cls[t >> 7][t & 127] = c[(size_t)bm0*128 + t];
    __syncthreads();
    { // kf[i][s] = c@wk + bk  (thread owns column s)
      const int s = tid;
      float a[16];
#pragma unroll
      for (int i = 0; i < 16; ++i) a[i] = 0.f;
      for (int l = 0; l < 128; ++l) {
        float w = wk[l*256 + s];
#pragma unroll
        for (int i = 0; i < 16; ++i) a[i] = fmaf(cls[i][l], w, a[i]);
      }
      float bks = bk[s];
#pragma unroll
      for (int i = 0; i < 16; ++i) kfl[i][s] = a[i] + bks;
    }
    { // vf: 2 threads per col, 8 latents each
      const int col = tid & 127, i0 = (tid >> 7) * 8;
      float a[8];
#pragma unroll
      for (int i = 0; i < 8; ++i) a[i] = 0.f;
      for (int l = 0; l < 128; ++l) {
        float w = wvw[l*128 + col];
#pragma unroll
        for (int i = 0; i < 8; ++i) a[i] = fmaf(cls[i0 + i][l], w, a[i]);
      }
      float bvc = bv[col];
      float cbf = 1.f + cb[col];
#pragma unroll
      for (int i = 0; i < 8; ++i) {
        float v = a[i] + bvc;
        vfh[(size_t)(bm0 + i0 + i)*128 + col] = (_Float16)v;
        evs[i0 + i][col] = v*cbf;
      }
    }
    __syncthreads();
    { // base = evs @ wv1 (2 threads per col, 8 latents each)
      const int col = tid & 127, i0 = (tid >> 7) * 8;
      float a[8];
#pragma unroll
      for (int i = 0; i < 8; ++i) a[i] = 0.f;
      for (int l = 0; l < 128; ++l) {
        float w = wv1[l*128 + col];
#pragma unroll
        for (int i = 0; i < 8; ++i) a[i] = fmaf(evs[i0 + i][l], w, a[i]);
      }
#pragma unroll
      for (int i = 0; i < 8; ++i)
        baseh[(size_t)(bm0 + i0 + i)*128 + col] = (_Float16)a[i];
    }
    // kw[a,h] = sum_q U[a][h*64+q] * kf[h*64+q] ; kb via E
    for (int col = tid; col < 524; col += 256) {
      float a[16];
#pragma unroll
      for (int i = 0; i < 16; ++i) a[i] = 0.f;
      if (col < 520) {
        int h = col / 130, aa = col - h*130;
        const float* ur = U + aa*256 + h*64;
        const float* kfh = &kfl[0][h*64];
        for (int q = 0; q < 64; ++q) {
          float w = ur[q];
#pragma unroll
          for (int i = 0; i < 16; ++i) a[i] = fmaf(kfl[i][h*64 + q], w, a[i]);
        }
        (void)kfh;
#pragma unroll
        for (int i = 0; i < 16; ++i)
          kwh[((size_t)(bm0 + i)*4 + h)*136 + aa] = (_Float16)a[i];
      } else {
        int h = col - 520;
        const float* er = E + h*64;
        for (int q = 0; q < 64; ++q) {
          float w = er[q];
#pragma unroll
          for (int i = 0; i < 16; ++i) a[i] = fmaf(kfl[i][h*64 + q], w, a[i]);
        }
#pragma unroll
        for (int i = 0; i < 16; ++i) kb[(size_t)(bm0 + i)*4 + h] = a[i];
      }
    }
  } else if (blk < 386) {
    // ---- W2f row a: left half copy, right half WB2 @ wv1 ----
    int a = blk - 256, j = tid;
    float acc;
    if (j < 128) {
      acc = W2A[a*256 + j];
    } else {
      int j2 = j - 128;
      acc = 0.f;
      for (int r = 0; r < 128; ++r) acc = fmaf(W2A[a*256 + 128 + r], wv1[r*128 + j2], acc);
    }
    W2f[w2f_idx(a, j, 5)] = (_Float16)acc;
  } else {
    // ---- consts: cgv | wvoT | outconst | W2f pad ----
    if (tid < 128) {
      float a2 = 0.f;
      for (int r = 0; r < 128; ++r)
        a2 = fmaf(bW[r] + b3v[128 + r], wv1[r*128 + tid], a2);
      cgv[tid] = a2 + bv1[tid];
    }
    for (int o = tid; o < 1536; o += 256) {
      int r12 = o >> 7, i = o & 127;
      int h = r12 / 3, cc = r12 - h*3;
      float acc = 0.f;
      for (int k = 0; k < 128; ++k)
        acc = fmaf(wv2[i*512 + h*128 + k], wout[(h*128 + k)*3 + cc], acc);
      wvoT_h[r12*128 + i] = (_Float16)acc;
    }
    for (int o = tid; o < 7680; o += 256) {
      int k = 130 + (o >> 8), n = o & 255;
      W2f[w2f_idx(k, n, 5)] = (_Float16)0.f;
    }
    if (tid < 3) {
      float acc = bout[tid];
      for (int r = 0; r < 512; ++r) acc = fmaf(bv2[r], wout[r*3 + tid], acc);
      outconst[tid] = acc;
    }
  }
}

// sfv B-fragment position: [nt(2)][ks(5)][lane(64)][i(8)] halfs
__device__ __forceinline__ int fragpos(int k, int e) {
  return ((((e >> 4)*5 + (k >> 5))*64 + (((k >> 3) & 3) << 4) + (e & 15)) << 3) + (k & 7);
}

// ---------- main kernel: one block per (b,n), batch->XCD swizzled ----------
__global__ __launch_bounds__(256, 8) void enf_main(
    const float* __restrict__ x, const float* __restrict__ p,
    const float* __restrict__ g,
    const float* __restrict__ w1q, const float* __restrict__ w1v,
    const _Float16* __restrict__ w2f, const _Float16* __restrict__ wv1f,
    const float* __restrict__ cgv, const _Float16* __restrict__ wvoT_h,
    const float* __restrict__ outconst,
    const _Float16* __restrict__ kwh, const float* __restrict__ kb,
    const _Float16* __restrict__ vfh, const _Float16* __restrict__ baseh,
    float* __restrict__ out) {
  // batch->XCD affinity: XCD = wgid%8 serves exactly one batch (b = (bid&7)>>1)
  const int bid = blockIdx.x;
  const int bn = (((bid & 7) >> 1) << 11) | ((bid & 1) << 10) | (bid >> 3);
  const int b = bn >> 11;          // N = 2048
  const int tid = threadIdx.x;
  const int lane = tid & 63;
  const int wid = tid >> 6;

  __shared__ alignas(16) float S[4640];
  __shared__ int   selm[K_];
  __shared__ float seld[K_];
  __shared__ float gkv[K_];
  __shared__ float bi0[K_], bi1[K_];
  __shared__ float logits_s[K_*HEADS_];
  __shared__ float hpart[HEADS_*4];

  float* candd = S;
  int*   candm = (int*)(S + 128);
  half2v* sfq2 = (half2v*)S;                 // [65][32] half2 words
  _Float16* sfvB = (_Float16*)(S + 2080);    // 5120 halfs
  _Float16* evlds = (_Float16*)S;            // [32][136]
  _Float16* gt_h  = (_Float16*)S + 4352;     // [32][136]
  float* poL   = S;                          // [32][12]

  const float x0 = x[bn*2 + 0];
  const float x1 = x[bn*2 + 1];
  const float2* pb2 = (const float2*)(p + (size_t)b*M_*2);

  // ---- Phase A: per-wave top-32 via binary-search threshold on float bits ----
  unsigned db[4]; int mm[4];
#pragma unroll
  for (int s = 0; s < 4; ++s) {
    int m = wid*256 + s*64 + lane;
    float2 pv = pb2[m];
    float d0 = x0 - pv.x, d1 = x1 - pv.y;
    float d = __fadd_rn(__fmul_rn(d0, d0), __fmul_rn(d1, d1));
    db[s] = __float_as_uint(d);
    mm[s] = m;
  }
  unsigned xth = 0;
  for (int bit = 30; bit >= 0; --bit) {
    unsigned trial = xth | (1u << bit);
    int cnt = __popcll(__ballot(db[0] < trial)) + __popcll(__ballot(db[1] < trial))
            + __popcll(__ballot(db[2] < trial)) + __popcll(__ballot(db[3] < trial));
    if (cnt < 32) xth = trial;
  }
  {
    ull bl[4], be[4];
#pragma unroll
    for (int s = 0; s < 4; ++s) {
      bl[s] = __ballot(db[s] < xth);
      be[s] = __ballot(db[s] == xth);
    }
    int r = __popcll(bl[0]) + __popcll(bl[1]) + __popcll(bl[2]) + __popcll(bl[3]);
    const ull lmask = (1ull << lane) - 1ull;
    int pl = 0, pe = 0;
#pragma unroll
    for (int s = 0; s < 4; ++s) {
      if (db[s] < xth) {
        int pos = pl + __popcll(bl[s] & lmask);
        candd[wid*K_ + pos] = __uint_as_float(db[s]);
        candm[wid*K_ + pos] = mm[s];
      } else if (db[s] == xth) {
        int pos = r + pe + __popcll(be[s] & lmask);
        if (pos < K_) {
          candd[wid*K_ + pos] = __uint_as_float(db[s]);
          candm[wid*K_ + pos] = mm[s];
        }
      }
      pl += __popcll(bl[s]);
      pe += __popcll(be[s]);
    }
  }
  __syncthreads();
  // merge: rank + fill selm/seld/gkv/bi in one pass
  if (tid < 128) {
    float d = candd[tid];
    int m = candm[tid];
    int rank = 0;
    for (int i = 0; i < 128; ++i) {
      float di = candd[i];
      rank += (di < d || (di == d && i < tid)) ? 1 : 0;
    }
    if (rank < K_) {
      selm[rank] = m; seld[rank] = d;
      gkv[rank] = g[(size_t)b*M_ + m];
      float2 pv = pb2[m];
      bi0[rank] = x0 - pv.x;
      bi1[rank] = x1 - pv.y;
    }
  }
  __syncthreads();

  // ---- Phase B: sin features, sfq fp16 half2 words, sfv fp16 B-frags ----
  if (tid < 32) {
    const int e = tid;
    half2v h;
    h[0] = (_Float16)__sinf(bi0[e]);
    h[1] = (_Float16)__sinf(bi1[e]);
    sfq2[e] = h;                      // word 0: k=0,1
    sfvB[fragpos(0, e)] = h[0];
    sfvB[fragpos(1, e)] = h[1];
  }
  for (int t = tid; t < 960; t += 256) {      // zero-pad sfv frags k=130..159
    int k = 130 + (t >> 5), e = t & 31;
    sfvB[fragpos(k, e)] = (_Float16)0.f;
  }
  {
    const int e = tid & 31;
    const int jg = tid >> 5;           // 0..7
    const float s0 = PI_F*(bi0[e] + 1.f), s1 = PI_F*(bi1[e] + 1.f);
#pragma unroll
    for (int t4 = 0; t4 < 4; ++t4) {
      const int J = 2*jg + 16*t4;      // even, covers 0..62
      float eqa = s0*w1q[J]     + s1*w1q[64 + J];
      float eqb = s0*w1q[J + 1] + s1*w1q[64 + J + 1];
      float eva = s0*w1v[J]     + s1*w1v[64 + J];
      float evb = s0*w1v[J + 1] + s1*w1v[64 + J + 1];
      half2v hs, hc;
      hs[0] = (_Float16)__sinf(eqa); hs[1] = (_Float16)__sinf(eqb);
      hc[0] = (_Float16)__cosf(eqa); hc[1] = (_Float16)__cosf(eqb);
      sfq2[(1 + (J >> 1))*32 + e]  = hs;   // k = 2+J, 3+J
      sfq2[(33 + (J >> 1))*32 + e] = hc;   // k = 66+J, 67+J
      sfvB[fragpos(2 + J, e)]  = (_Float16)__sinf(eva);
      sfvB[fragpos(3 + J, e)]  = (_Float16)__sinf(evb);
      sfvB[fragpos(66 + J, e)] = (_Float16)__cosf(eva);
      sfvB[fragpos(67 + J, e)] = (_Float16)__cosf(evb);
    }
  }
  __syncthreads();

  // ---- Phase C: attention logits via v_dot2_f32_f16 (waves 0,1) ----
  if (tid < 128) {
    const int e = tid >> 2, h = tid & 3;
    const int m = selm[e];
    const _Float16* kwrow = kwh + ((size_t)((b*M_ + m)*4 + h))*136;
    float accq = kb[(size_t)(b*M_ + m)*4 + h];
    const half8* kw8 = (const half8*)kwrow;
    const half2v* sq = sfq2 + e;
#pragma unroll 4
    for (int q8 = 0; q8 < 16; ++q8) {
      half8 kv = kw8[q8];
      half2v k0; k0[0] = kv[0]; k0[1] = kv[1];
      half2v k1; k1[0] = kv[2]; k1[1] = kv[3];
      half2v k2; k2[0] = kv[4]; k2[1] = kv[5];
      half2v k3; k3[0] = kv[6]; k3[1] = kv[7];
      accq = __builtin_amdgcn_fdot2(sq[(4*q8 + 0)*32], k0, accq, false);
      accq = __builtin_amdgcn_fdot2(sq[(4*q8 + 1)*32], k1, accq, false);
      accq = __builtin_amdgcn_fdot2(sq[(4*q8 + 2)*32], k2, accq, false);
      accq = __builtin_amdgcn_fdot2(sq[(4*q8 + 3)*32], k3, accq, false);
    }
    {
      half2v kt = *(const half2v*)(kwrow + 128);
      accq = __builtin_amdgcn_fdot2(sq[64*32], kt, accq, false);
    }
    const float gk = gkv[e];
    logits_s[tid] = accq - seld[e]/(gk*gk);
  }

  // ---- GEMM1 (MFMA): C1T = W2^T @ sfv^T
  f32x4 acc1[4][2];
#pragma unroll
  for (int mi = 0; mi < 4; ++mi)
#pragma unroll
    for (int nt = 0; nt < 2; ++nt) acc1[mi][nt] = (f32x4)0.f;
  {
    const half8* w2f8  = (const half8*)w2f;
    const half8* sfvB8 = (const half8*)sfvB;
#pragma unroll
    for (int ks = 0; ks < 5; ++ks) {
      half8 bf0 = sfvB8[(0*5 + ks)*64 + lane];
      half8 bf1 = sfvB8[(1*5 + ks)*64 + lane];
#pragma unroll
      for (int mi = 0; mi < 4; ++mi) {
        const int mt = (mi < 2) ? (2*wid + mi) : (8 + 2*wid + (mi - 2));
        half8 af = w2f8[(mt*5 + ks)*64 + lane];
        acc1[mi][0] = __builtin_amdgcn_mfma_f32_16x16x32_f16(af, bf0, acc1[mi][0], 0, 0, 0);
        acc1[mi][1] = __builtin_amdgcn_mfma_f32_16x16x32_f16(af, bf1, acc1[mi][1], 0, 0, 0);
      }
    }
  }
  __syncthreads();   // sfq + sfvB dead

  // ---- epilogue: evec (mi 0,1) -> evlds fp16; gterm (mi 2,3) -> registers ----
  f32x4 tg[2][2];
#pragma unroll
  for (int mi = 0; mi < 2; ++mi) {
    const int j0 = (2*wid + mi)*16 + ((lane >> 4) << 2);
#pragma unroll
    for (int nt = 0; nt < 2; ++nt) {
      const int e = nt*16 + (lane & 15);
      const half4v v4 = *(const half4v*)(vfh + ((size_t)(b*M_ + selm[e]))*NH_ + j0);
      f32x4 a = acc1[mi][nt];
      half4v hv;
      hv[0] = (_Float16)((float)v4[0] * a[0]);
      hv[1] = (_Float16)((float)v4[1] * a[1]);
      hv[2] = (_Float16)((float)v4[2] * a[2]);
      hv[3] = (_Float16)((float)v4[3] * a[3]);
      *(half4v*)(evlds + e*136 + j0) = hv;
    }
  }
#pragma unroll
  for (int mi = 0; mi < 2; ++mi) {
    const int j0 = 32*wid + mi*16 + ((lane >> 4) << 2);
    const float4 c4 = *(const float4*)(cgv + j0);
#pragma unroll
    for (int nt = 0; nt < 2; ++nt) {
      const int e = nt*16 + (lane & 15);
      const half4v b4 = *(const half4v*)(baseh + ((size_t)(b*M_ + selm[e]))*NH_ + j0);
      f32x4 a = acc1[2 + mi][nt];
      tg[mi][nt][0] = a[0] + (float)b4[0] + c4.x;
      tg[mi][nt][1] = a[1] + (float)b4[1] + c4.y;
      tg[mi][nt][2] = a[2] + (float)b4[2] + c4.z;
      tg[mi][nt][3] = a[3] + (float)b4[3] + c4.w;
    }
  }
  __syncthreads();

  // ---- GEMM2 (MFMA): acc = tg + wv1^T @ ev^T ----
  {
    const half8* wv1f8 = (const half8*)wv1f;
    const half8* evB   = (const half8*)evlds;   // index: e*17 + ks*4 + (lane>>4)
#pragma unroll
    for (int ks = 0; ks < 4; ++ks) {
      half8 bf0 = evB[(lane & 15)*17 + ks*4 + (lane >> 4)];
      half8 bf1 = evB[(16 + (lane & 15))*17 + ks*4 + (lane >> 4)];
#pragma unroll
      for (int mi = 0; mi < 2; ++mi) {
        half8 af = wv1f8[((2*wid + mi)*4 + ks)*64 + lane];
        tg[mi][0] = __builtin_amdgcn_mfma_f32_16x16x32_f16(af, bf0, tg[mi][0], 0, 0, 0);
        tg[mi][1] = __builtin_amdgcn_mfma_f32_16x16x32_f16(af, bf1, tg[mi][1], 0, 0, 0);
      }
    }
  }
  // gelu epilogue -> gt fp16 (disjoint from evlds; no barrier needed)
#pragma unroll
  for (int mi = 0; mi < 2; ++mi) {
    const int j0 = (2*wid + mi)*16 + ((lane >> 4) << 2);
#pragma unroll
    for (int nt = 0; nt < 2; ++nt) {
      const int e = nt*16 + (lane & 15);
      f32x4 a = tg[mi][nt];
      half4v gv;
#pragma unroll
      for (int jj = 0; jj < 4; ++jj) {
        float tval = a[jj];
        float u = 0.79788456080286536f*(tval + 0.044715f*tval*tval*tval);
        float ex = __expf(2.f*u);
        float th = 1.f - 2.f/(ex + 1.f);
        gv[jj] = (_Float16)(0.5f*tval*(1.f + th));
      }
      *(half4v*)(gt_h + e*136 + j0) = gv;
    }
  }
  __syncthreads();

  // ---- Phase F: po[e][12] = gt[e] @ wvoT^T via v_dot2_f32_f16 ----
  for (int t = tid; t < K_*12; t += 256) {
    const int e = t / 12, r = t - (t/12)*12;
    const half8* wr8 = (const half8*)(wvoT_h + r*NH_);
    const half8* gr8 = (const half8*)(gt_h + e*136);
    float a0 = 0.f, a1 = 0.f, a2 = 0.f, a3 = 0.f;
#pragma unroll 4
    for (int q = 0; q < 16; ++q) {
      half8 gq = gr8[q];
      half8 wq = wr8[q];
      half2v g0; g0[0] = gq[0]; g0[1] = gq[1];
      half2v g1; g1[0] = gq[2]; g1[1] = gq[3];
      half2v g2; g2[0] = gq[4]; g2[1] = gq[5];
      half2v g3; g3[0] = gq[6]; g3[1] = gq[7];
      half2v w0; w0[0] = wq[0]; w0[1] = wq[1];
      half2v w1; w1[0] = wq[2]; w1[1] = wq[3];
      half2v w2; w2[0] = wq[4]; w2[1] = wq[5];
      half2v w3; w3[0] = wq[6]; w3[1] = wq[7];
      a0 = __builtin_amdgcn_fdot2(g0, w0, a0, false);
      a1 = __builtin_amdgcn_fdot2(g1, w1, a1, false);
      a2 = __builtin_amdgcn_fdot2(g2, w2, a2, false);
      a3 = __builtin_amdgcn_fdot2(g3, w3, a3, false);
    }
    poL[t] = (a0 + a1) + (a2 + a3);
  }
  __syncthreads();

  // ---- Phase G: softmax over K per head + combine ----
  if (tid < 128) {
    const int h = tid >> 5, e = tid & 31;
    float l = logits_s[e*4 + h];
    float mx = l;
#pragma unroll
    for (int off = 1; off < 32; off <<= 1) mx = fmaxf(mx, __shfl_xor(mx, off));
    float w = __expf(l - mx);
    float s = w;
#pragma unroll
    for (int off = 1; off < 32; off <<= 1) s += __shfl_xor(s, off);
    float att = w / s;
    float p0 = att * poL[e*12 + h*3 + 0];
    float p1 = att * poL[e*12 + h*3 + 1];
    float p2 = att * poL[e*12 + h*3 + 2];
#pragma unroll
    for (int off = 1; off < 32; off <<= 1) {
      p0 += __shfl_xor(p0, off);
      p1 += __shfl_xor(p1, off);
      p2 += __shfl_xor(p2, off);
    }
    if (e == 0) { hpart[h*4 + 0] = p0; hpart[h*4 + 1] = p1; hpart[h*4 + 2] = p2; }
  }
  __syncthreads();
  if (tid < 3) {
    out[(size_t)bn*3 + tid] = outconst[tid]
        + hpart[0*4 + tid] + hpart[1*4 + tid] + hpart[2*4 + tid] + hpart[3*4 + tid];
  }
}

extern "C" void kernel_launch(void* const* d_in, const int* in_sizes, int n_in,
                              void* d_out, int out_size, void* d_ws, size_t ws_size,
                              hipStream_t stream) {
  (void)in_sizes; (void)n_in; (void)out_size; (void)ws_size;
  const float* x    = (const float*)d_in[0];
  const float* p    = (const float*)d_in[1];
  const float* c    = (const float*)d_in[2];
  const float* g    = (const float*)d_in[3];
  const float* w1q  = (const float*)d_in[4];
  const float* w2q  = (const float*)d_in[5];
  const float* b2q  = (const float*)d_in[6];
  const float* w3q  = (const float*)d_in[7];
  const float* b3q  = (const float*)d_in[8];
  const float* w1v  = (const float*)d_in[9];
  const float* w2v  = (const float*)d_in[10];
  const float* b2v  = (const float*)d_in[11];
  const float* w3v  = (const float*)d_in[12];
  const float* b3v  = (const float*)d_in[13];
  const float* wk   = (const float*)d_in[14];
  const float* bk   = (const float*)d_in[15];
  const float* wvw  = (const float*)d_in[16];
  const float* bv   = (const float*)d_in[17];
  const float* wv1  = (const float*)d_in[18];
  const float* bv1  = (const float*)d_in[19];
  const float* wv2  = (const float*)d_in[20];
  const float* bv2  = (const float*)d_in[21];
  const float* wout = (const float*)d_in[22];
  const float* bout = (const float*)d_in[23];
  float* ws = (float*)d_ws;
  float* outp = (float*)d_out;

  hipLaunchKernelGGL(enf_preA, dim3(325), dim3(256), 0, stream,
                     w2q, w3q, b2q, b3q, w2v, w3v, b2v, b3v, wv1,
                     ws + OFF_U, ws + OFF_E, ws + OFF_CB, ws + OFF_BW,
                     ws + OFF_W2A, (_Float16*)(ws + OFF_WV1F));
  hipLaunchKernelGGL(enf_preBL, dim3(387), dim3(256), 0, stream,
                     c, wk, bk, wvw, bv, wv1,
                     ws + OFF_U, ws + OFF_E, ws + OFF_CB, ws + OFF_BW,
                     ws + OFF_W2A, b3v, bv1, wv2, wout, bv2, bout,
                     (_Float16*)(ws + OFF_W2F), ws + OFF_CGV,
                     (_Float16*)(ws + OFF_WVOTH), ws + OFF_OUTC,
                     (_Float16*)(ws + OFF_KWH), ws + OFF_KB,
                     (_Float16*)(ws + OFF_VFH), (_Float16*)(ws + OFF_BASEH));
  hipLaunchKernelGGL(enf_main, dim3(B_*N_), dim3(256), 0, stream,
                     x, p, g, w1q, w1v,
                     (const _Float16*)(ws + OFF_W2F), (const _Float16*)(ws + OFF_WV1F),
                     ws + OFF_CGV, (const _Float16*)(ws + OFF_WVOTH), ws + OFF_OUTC,
                     (const _Float16*)(ws + OFF_KWH), ws + OFF_KB,
                     (const _Float16*)(ws + OFF_VFH), (const _Float16*)(ws + OFF_BASEH),
                     outp);
}

// Round 12
// 196.341 us; speedup vs baseline: 1.8845x; 1.3899x over previous
//
#include <hip/hip_runtime.h>
#include <math.h>

#define B_ 4
#define N_ 2048
#define M_ 1024
#define K_ 32
#define HEADS_ 4
#define NH_ 128
#define PI_F 3.14159265358979323846f

typedef unsigned long long ull;
typedef __attribute__((ext_vector_type(8))) _Float16 half8;
typedef __attribute__((ext_vector_type(4))) _Float16 half4v;
typedef __attribute__((ext_vector_type(2))) _Float16 half2v;
typedef __attribute__((ext_vector_type(4))) float f32x4;

// workspace offsets (in floats)
#define OFF_CB     0         // 128
#define OFF_CGV    128       // 128
#define OFF_WVOF   256       // 1024 (2048 halfs: wvoT^T MFMA B-frags)
#define OFF_OUTC   1280      // 4
#define OFF_BW     1284      // 128
#define OFF_E      1412      // 256
#define OFF_KB     1668      // 16384
#define OFF_U      18052     // 33280
#define OFF_W2A    51332     // 33280
#define OFF_W2F    84612     // 20480 (40960 halfs)
#define OFF_WV1F   105092    // 8192 (16384 halfs)
#define OFF_BASEH  113284    // 262144 (B*M*128 halfs)
#define OFF_KWH    375428    // 1114112 (B*M*4*136 halfs)
#define OFF_VFH    1489540   // 262144 (B*M*128 halfs)
// total = 1751684 floats (~7.0 MB)

// W2f/wv1f fragment index for (k, n): [mt][ks][lane][i]
__device__ __forceinline__ int w2f_idx(int k, int n, int nks) {
  int mt = n >> 4, ks = k >> 5;
  int lane = (((k >> 3) & 3) << 4) | (n & 15);
  return (((mt*nks + ks)*64 + lane) << 3) + (k & 7);
}

// ---------- preA: U | E+cb+bW | W2A | wv1f  (no internal deps) ----------
__global__ __launch_bounds__(256) void enf_preA(
    const float* __restrict__ w2q, const float* __restrict__ w3q,
    const float* __restrict__ b2q, const float* __restrict__ b3q,
    const float* __restrict__ w2v, const float* __restrict__ w3v,
    const float* __restrict__ b2v, const float* __restrict__ b3v,
    const float* __restrict__ wv1,
    float* __restrict__ U, float* __restrict__ E, float* __restrict__ cb,
    float* __restrict__ bW, float* __restrict__ W2A,
    _Float16* __restrict__ wv1f) {
  const int blk = blockIdx.x, tid = threadIdx.x;
  if (blk < 130) {               // U[a][s] = w2q @ w3q
    int a = blk, s = tid;
    float acc = 0.f;
    for (int i = 0; i < 128; ++i) acc = fmaf(w2q[a*128 + i], w3q[i*256 + s], acc);
    U[a*256 + s] = acc;
  } else if (blk == 130) {       // E | cb | bW
    int s = tid;
    float acc = b3q[s];
    for (int j = 0; j < 128; ++j) acc = fmaf(b2q[j], w3q[j*256 + s], acc);
    E[s] = acc;
    if (tid < 128) {
      float a1 = 0.f, a2 = 0.f;
      for (int i = 0; i < 128; ++i) {
        a1 = fmaf(b2v[i], w3v[i*256 + tid], a1);
        a2 = fmaf(b2v[i], w3v[i*256 + 128 + tid], a2);
      }
      cb[tid] = a1 + b3v[tid];
      bW[tid] = a2;
    }
  } else if (blk < 261) {        // W2A[a][j] = w2v @ w3v (both halves)
    int a = blk - 131, j = tid;
    float acc = 0.f;
    for (int i = 0; i < 128; ++i) acc = fmaf(w2v[a*128 + i], w3v[i*256 + j], acc);
    W2A[a*256 + j] = acc;
  } else {                       // wv1f frags: [mt8][ks4][lane64][i8], blocks 261..324
    int idx = (blk - 261)*256 + tid;
    int i = idx & 7, lane = (idx >> 3) & 63;
    int rest = idx >> 9;
    int ks = rest & 3, mt = rest >> 2;
    int k = ks*32 + ((lane >> 4) << 3) + i;
    int j = mt*16 + (lane & 15);
    wv1f[idx] = (_Float16)wv1[k*128 + j];
  }
}

// ---------- preBL: latent tables (256 blk) | W2f (130 blk) | consts (1 blk) ----------
__global__ __launch_bounds__(256) void enf_preBL(
    const float* __restrict__ c, const float* __restrict__ wk,
    const float* __restrict__ bk, const float* __restrict__ wvw,
    const float* __restrict__ bv, const float* __restrict__ wv1,
    const float* __restrict__ U, const float* __restrict__ E,
    const float* __restrict__ cb, const float* __restrict__ bW,
    const float* __restrict__ W2A, const float* __restrict__ b3v,
    const float* __restrict__ bv1, const float* __restrict__ wv2,
    const float* __restrict__ wout, const float* __restrict__ bv2,
    const float* __restrict__ bout,
    _Float16* __restrict__ W2f, float* __restrict__ cgv,
    _Float16* __restrict__ wvoF, float* __restrict__ outconst,
    _Float16* __restrict__ kwh, float* __restrict__ kb,
    _Float16* __restrict__ vfh, _Float16* __restrict__ baseh) {
  const int blk = blockIdx.x, tid = threadIdx.x;
  __shared__ float cls[16][128];
  __shared__ float kfl[16][256];
  __shared__ float evs[16][128];
  if (blk < 256) {
    // ---- latent: 16 latents per block ----
    const int bm0 = blk * 16;
    for (int t = tid; t < 2048; t += 256) cls[t >> 7][t & 127] = c[(size_t)bm0*128 + t];
    __syncthreads();
    { // kf[i][s] = c@wk + bk  (thread owns column s)
      const int s = tid;
      float a[16];
#pragma unroll
      for (int i = 0; i < 16; ++i) a[i] = 0.f;
      for (int l = 0; l < 128; ++l) {
        float w = wk[l*256 + s];
#pragma unroll
        for (int i = 0; i < 16; ++i) a[i] = fmaf(cls[i][l], w, a[i]);
      }
      float bks = bk[s];
#pragma unroll
      for (int i = 0; i < 16; ++i) kfl[i][s] = a[i] + bks;
    }
    { // vf: 2 threads per col, 8 latents each
      const int col = tid & 127, i0 = (tid >> 7) * 8;
      float a[8];
#pragma unroll
      for (int i = 0; i < 8; ++i) a[i] = 0.f;
      for (int l = 0; l < 128; ++l) {
        float w = wvw[l*128 + col];
#pragma unroll
        for (int i = 0; i < 8; ++i) a[i] = fmaf(cls[i0 + i][l], w, a[i]);
      }
      float bvc = bv[col];
      float cbf = 1.f + cb[col];
#pragma unroll
      for (int i = 0; i < 8; ++i) {
        float v = a[i] + bvc;
        vfh[(size_t)(bm0 + i0 + i)*128 + col] = (_Float16)v;
        evs[i0 + i][col] = v*cbf;
      }
    }
    __syncthreads();
    { // base = evs @ wv1 (2 threads per col, 8 latents each)
      const int col = tid & 127, i0 = (tid >> 7) * 8;
      float a[8];
#pragma unroll
      for (int i = 0; i < 8; ++i) a[i] = 0.f;
      for (int l = 0; l < 128; ++l) {
        float w = wv1[l*128 + col];
#pragma unroll
        for (int i = 0; i < 8; ++i) a[i] = fmaf(evs[i0 + i][l], w, a[i]);
      }
#pragma unroll
      for (int i = 0; i < 8; ++i)
        baseh[(size_t)(bm0 + i0 + i)*128 + col] = (_Float16)a[i];
    }
    // kw[a,h] = sum_q U[a][h*64+q] * kf[h*64+q] ; kb via E
    for (int col = tid; col < 524; col += 256) {
      float a[16];
#pragma unroll
      for (int i = 0; i < 16; ++i) a[i] = 0.f;
      if (col < 520) {
        int h = col / 130, aa = col - h*130;
        const float* ur = U + aa*256 + h*64;
        for (int q = 0; q < 64; ++q) {
          float w = ur[q];
#pragma unroll
          for (int i = 0; i < 16; ++i) a[i] = fmaf(kfl[i][h*64 + q], w, a[i]);
        }
#pragma unroll
        for (int i = 0; i < 16; ++i)
          kwh[((size_t)(bm0 + i)*4 + h)*136 + aa] = (_Float16)a[i];
      } else {
        int h = col - 520;
        const float* er = E + h*64;
        for (int q = 0; q < 64; ++q) {
          float w = er[q];
#pragma unroll
          for (int i = 0; i < 16; ++i) a[i] = fmaf(kfl[i][h*64 + q], w, a[i]);
        }
#pragma unroll
        for (int i = 0; i < 16; ++i) kb[(size_t)(bm0 + i)*4 + h] = a[i];
      }
    }
  } else if (blk < 386) {
    // ---- W2f row a: left half copy, right half WB2 @ wv1 ----
    int a = blk - 256, j = tid;
    float acc;
    if (j < 128) {
      acc = W2A[a*256 + j];
    } else {
      int j2 = j - 128;
      acc = 0.f;
      for (int r = 0; r < 128; ++r) acc = fmaf(W2A[a*256 + 128 + r], wv1[r*128 + j2], acc);
    }
    W2f[w2f_idx(a, j, 5)] = (_Float16)acc;
  } else {
    // ---- consts: cgv | wvoF (frag layout) | outconst | W2f pad ----
    float* wvs = &cls[0][0];       // 12*128 fp32 scratch (block-local)
    if (tid < 128) {
      float a2 = 0.f;
      for (int r = 0; r < 128; ++r)
        a2 = fmaf(bW[r] + b3v[128 + r], wv1[r*128 + tid], a2);
      cgv[tid] = a2 + bv1[tid];
    }
    for (int o = tid; o < 1536; o += 256) {
      int r12 = o >> 7, i = o & 127;
      int h = r12 / 3, cc = r12 - h*3;
      float acc = 0.f;
      for (int k = 0; k < 128; ++k)
        acc = fmaf(wv2[i*512 + h*128 + k], wout[(h*128 + k)*3 + cc], acc);
      wvs[r12*128 + i] = acc;
    }
    for (int o = tid; o < 7680; o += 256) {
      int k = 130 + (o >> 8), n = o & 255;
      W2f[w2f_idx(k, n, 5)] = (_Float16)0.f;
    }
    if (tid < 3) {
      float acc = bout[tid];
      for (int r = 0; r < 512; ++r) acc = fmaf(bv2[r], wout[r*3 + tid], acc);
      outconst[tid] = acc;
    }
    __syncthreads();
    // wvoF[ks4][lane64][i8]: B[k][n] = wvoT[n][k] (n<12), 0 else
    for (int idx = tid; idx < 2048; idx += 256) {
      int i = idx & 7, lane = (idx >> 3) & 63, ks = idx >> 9;
      int k = ks*32 + ((lane >> 4) << 3) + i;
      int n = lane & 15;
      wvoF[idx] = (n < 12) ? (_Float16)wvs[n*128 + k] : (_Float16)0.f;
    }
  }
}

// sfv B-fragment position: [nt(2)][ks(5)][lane(64)][i(8)] halfs
__device__ __forceinline__ int fragpos(int k, int e) {
  return ((((e >> 4)*5 + (k >> 5))*64 + (((k >> 3) & 3) << 4) + (e & 15)) << 3) + (k & 7);
}

// ---------- main kernel: one block per (b,n), batch->XCD swizzled ----------
__global__ __launch_bounds__(256, 8) void enf_main(
    const float* __restrict__ x, const float* __restrict__ p,
    const float* __restrict__ g,
    const float* __restrict__ w1q, const float* __restrict__ w1v,
    const _Float16* __restrict__ w2f, const _Float16* __restrict__ wv1f,
    const float* __restrict__ cgv, const _Float16* __restrict__ wvoF,
    const float* __restrict__ outconst,
    const _Float16* __restrict__ kwh, const float* __restrict__ kb,
    const _Float16* __restrict__ vfh, const _Float16* __restrict__ baseh,
    float* __restrict__ out) {
  // batch->XCD affinity: XCD = wgid%8 serves exactly one batch (b = (bid&7)>>1)
  const int bid = blockIdx.x;
  const int bn = (((bid & 7) >> 1) << 11) | ((bid & 1) << 10) | (bid >> 3);
  const int b = bn >> 11;          // N = 2048
  const int tid = threadIdx.x;
  const int lane = tid & 63;
  const int wid = tid >> 6;

  // S timeline (bytes):
  //  phase1: sfq2 half2[32][68] @ [0,8704) | sfvB 5120 halfs @ [8704,18944)
  //  phase2: evlds half[32][136] @ [0,8704) | gt fp16 [32][136] @ [8704,17408)
  //  phase3: poL fp32 [384] @ [0,1536)
  __shared__ alignas(16) float S[4736];
  __shared__ int   selm[K_];
  __shared__ float seld[K_];
  __shared__ float gkv[K_];
  __shared__ float bi0[K_], bi1[K_];
  __shared__ float logits_s[K_*HEADS_];
  __shared__ float hpart[HEADS_*4];

  float* candd = S;
  int*   candm = (int*)(S + 128);
  half2v* sfq2 = (half2v*)S;                 // [32][68] half2 words (w = k>>1)
  _Float16* sfvB = (_Float16*)(S + 2176);    // 5120 halfs
  _Float16* evlds = (_Float16*)S;            // [32][136]
  _Float16* gt_h  = (_Float16*)S + 4352;     // [32][136]
  float* poL   = S;                          // [32][12]

  const float x0 = x[bn*2 + 0];
  const float x1 = x[bn*2 + 1];
  const float2* pb2 = (const float2*)(p + (size_t)b*M_*2);

  // ---- Phase A: per-wave top-32 via binary-search threshold on float bits ----
  unsigned db[4]; int mm[4];
#pragma unroll
  for (int s = 0; s < 4; ++s) {
    int m = wid*256 + s*64 + lane;
    float2 pv = pb2[m];
    float d0 = x0 - pv.x, d1 = x1 - pv.y;
    float d = __fadd_rn(__fmul_rn(d0, d0), __fmul_rn(d1, d1));
    db[s] = __float_as_uint(d);
    mm[s] = m;
  }
  unsigned xth = 0;
  for (int bit = 30; bit >= 0; --bit) {
    unsigned trial = xth | (1u << bit);
    int cnt = __popcll(__ballot(db[0] < trial)) + __popcll(__ballot(db[1] < trial))
            + __popcll(__ballot(db[2] < trial)) + __popcll(__ballot(db[3] < trial));
    if (cnt < 32) xth = trial;
  }
  {
    ull bl[4], be[4];
#pragma unroll
    for (int s = 0; s < 4; ++s) {
      bl[s] = __ballot(db[s] < xth);
      be[s] = __ballot(db[s] == xth);
    }
    int r = __popcll(bl[0]) + __popcll(bl[1]) + __popcll(bl[2]) + __popcll(bl[3]);
    const ull lmask = (1ull << lane) - 1ull;
    int pl = 0, pe = 0;
#pragma unroll
    for (int s = 0; s < 4; ++s) {
      if (db[s] < xth) {
        int pos = pl + __popcll(bl[s] & lmask);
        candd[wid*K_ + pos] = __uint_as_float(db[s]);
        candm[wid*K_ + pos] = mm[s];
      } else if (db[s] == xth) {
        int pos = r + pe + __popcll(be[s] & lmask);
        if (pos < K_) {
          candd[wid*K_ + pos] = __uint_as_float(db[s]);
          candm[wid*K_ + pos] = mm[s];
        }
      }
      pl += __popcll(bl[s]);
      pe += __popcll(be[s]);
    }
  }
  __syncthreads();
  // merge: linear rank scan (lists are NOT value-sorted!), float4-vectorized
  if (tid < 128) {
    float d = candd[tid];
    int m = candm[tid];
    int rank = 0;
    const float4* c4 = (const float4*)candd;
#pragma unroll 8
    for (int i = 0; i < 32; ++i) {
      float4 v = c4[i];
      int base = i*4;
      rank += (v.x < d || (v.x == d && base + 0 < tid)) ? 1 : 0;
      rank += (v.y < d || (v.y == d && base + 1 < tid)) ? 1 : 0;
      rank += (v.z < d || (v.z == d && base + 2 < tid)) ? 1 : 0;
      rank += (v.w < d || (v.w == d && base + 3 < tid)) ? 1 : 0;
    }
    if (rank < K_) {
      selm[rank] = m; seld[rank] = d;
      gkv[rank] = g[(size_t)b*M_ + m];
      float2 pv = pb2[m];
      bi0[rank] = x0 - pv.x;
      bi1[rank] = x1 - pv.y;
    }
  }
  __syncthreads();

  // ---- Phase B: sin features, sfq2 [e][68] half2 words, sfv fp16 B-frags ----
  if (tid < 32) {
    const int e = tid;
    half2v h;
    h[0] = (_Float16)__sinf(bi0[e]);
    h[1] = (_Float16)__sinf(bi1[e]);
    sfq2[e*68 + 0] = h;               // word 0: k=0,1
    sfvB[fragpos(0, e)] = h[0];
    sfvB[fragpos(1, e)] = h[1];
  }
  for (int t = tid; t < 960; t += 256) {      // zero-pad sfv frags k=130..159
    int k = 130 + (t >> 5), e = t & 31;
    sfvB[fragpos(k, e)] = (_Float16)0.f;
  }
  {
    const int e = tid & 31;
    const int jg = tid >> 5;           // 0..7
    const float s0 = PI_F*(bi0[e] + 1.f), s1 = PI_F*(bi1[e] + 1.f);
#pragma unroll
    for (int t4 = 0; t4 < 4; ++t4) {
      const int J = 2*jg + 16*t4;      // even, covers 0..62
      float eqa = s0*w1q[J]     + s1*w1q[64 + J];
      float eqb = s0*w1q[J + 1] + s1*w1q[64 + J + 1];
      float eva = s0*w1v[J]     + s1*w1v[64 + J];
      float evb = s0*w1v[J + 1] + s1*w1v[64 + J + 1];
      half2v hs, hc;
      hs[0] = (_Float16)__sinf(eqa); hs[1] = (_Float16)__sinf(eqb);
      hc[0] = (_Float16)__cosf(eqa); hc[1] = (_Float16)__cosf(eqb);
      sfq2[e*68 + 1 + (J >> 1)]  = hs;   // k = 2+J, 3+J
      sfq2[e*68 + 33 + (J >> 1)] = hc;   // k = 66+J, 67+J
      sfvB[fragpos(2 + J, e)]  = (_Float16)__sinf(eva);
      sfvB[fragpos(3 + J, e)]  = (_Float16)__sinf(evb);
      sfvB[fragpos(66 + J, e)] = (_Float16)__cosf(eva);
      sfvB[fragpos(67 + J, e)] = (_Float16)__cosf(evb);
    }
  }
  __syncthreads();

  // ---- Phase C: attention logits via b128 sfq reads + v_dot2 (waves 0,1) ----
  if (tid < 128) {
    const int e = tid >> 2, h = tid & 3;
    const int m = selm[e];
    const _Float16* kwrow = kwh + ((size_t)((b*M_ + m)*4 + h))*136;
    float accq = kb[(size_t)(b*M_ + m)*4 + h];
    const half8* kw8 = (const half8*)kwrow;
    const half8* sq8 = (const half8*)(sfq2 + e*68);
#pragma unroll 4
    for (int q8 = 0; q8 < 16; ++q8) {
      half8 kv = kw8[q8];
      half8 sv = sq8[q8];
      half2v k0; k0[0] = kv[0]; k0[1] = kv[1];
      half2v k1; k1[0] = kv[2]; k1[1] = kv[3];
      half2v k2; k2[0] = kv[4]; k2[1] = kv[5];
      half2v k3; k3[0] = kv[6]; k3[1] = kv[7];
      half2v s0; s0[0] = sv[0]; s0[1] = sv[1];
      half2v s1; s1[0] = sv[2]; s1[1] = sv[3];
      half2v s2; s2[0] = sv[4]; s2[1] = sv[5];
      half2v s3; s3[0] = sv[6]; s3[1] = sv[7];
      accq = __builtin_amdgcn_fdot2(s0, k0, accq, false);
      accq = __builtin_amdgcn_fdot2(s1, k1, accq, false);
      accq = __builtin_amdgcn_fdot2(s2, k2, accq, false);
      accq = __builtin_amdgcn_fdot2(s3, k3, accq, false);
    }
    {
      half2v kt = *(const half2v*)(kwrow + 128);
      accq = __builtin_amdgcn_fdot2(sfq2[e*68 + 64], kt, accq, false);
    }
    const float gk = gkv[e];
    logits_s[tid] = accq - seld[e]/(gk*gk);
  }

  // ---- GEMM1 (MFMA): C1T = W2^T @ sfv^T
  f32x4 acc1[4][2];
#pragma unroll
  for (int mi = 0; mi < 4; ++mi)
#pragma unroll
    for (int nt = 0; nt < 2; ++nt) acc1[mi][nt] = (f32x4)0.f;
  {
    const half8* w2f8  = (const half8*)w2f;
    const half8* sfvB8 = (const half8*)sfvB;
#pragma unroll
    for (int ks = 0; ks < 5; ++ks) {
      half8 bf0 = sfvB8[(0*5 + ks)*64 + lane];
      half8 bf1 = sfvB8[(1*5 + ks)*64 + lane];
#pragma unroll
      for (int mi = 0; mi < 4; ++mi) {
        const int mt = (mi < 2) ? (2*wid + mi) : (8 + 2*wid + (mi - 2));
        half8 af = w2f8[(mt*5 + ks)*64 + lane];
        acc1[mi][0] = __builtin_amdgcn_mfma_f32_16x16x32_f16(af, bf0, acc1[mi][0], 0, 0, 0);
        acc1[mi][1] = __builtin_amdgcn_mfma_f32_16x16x32_f16(af, bf1, acc1[mi][1], 0, 0, 0);
      }
    }
  }
  __syncthreads();   // sfq2 + sfvB dead

  // ---- epilogue: evec (mi 0,1) -> evlds fp16; gterm (mi 2,3) -> registers ----
  f32x4 tg[2][2];
#pragma unroll
  for (int mi = 0; mi < 2; ++mi) {
    const int j0 = (2*wid + mi)*16 + ((lane >> 4) << 2);
#pragma unroll
    for (int nt = 0; nt < 2; ++nt) {
      const int e = nt*16 + (lane & 15);
      const half4v v4 = *(const half4v*)(vfh + ((size_t)(b*M_ + selm[e]))*NH_ + j0);
      f32x4 a = acc1[mi][nt];
      half4v hv;
      hv[0] = (_Float16)((float)v4[0] * a[0]);
      hv[1] = (_Float16)((float)v4[1] * a[1]);
      hv[2] = (_Float16)((float)v4[2] * a[2]);
      hv[3] = (_Float16)((float)v4[3] * a[3]);
      *(half4v*)(evlds + e*136 + j0) = hv;
    }
  }
#pragma unroll
  for (int mi = 0; mi < 2; ++mi) {
    const int j0 = 32*wid + mi*16 + ((lane >> 4) << 2);
    const float4 c4 = *(const float4*)(cgv + j0);
#pragma unroll
    for (int nt = 0; nt < 2; ++nt) {
      const int e = nt*16 + (lane & 15);
      const half4v b4 = *(const half4v*)(baseh + ((size_t)(b*M_ + selm[e]))*NH_ + j0);
      f32x4 a = acc1[2 + mi][nt];
      tg[mi][nt][0] = a[0] + (float)b4[0] + c4.x;
      tg[mi][nt][1] = a[1] + (float)b4[1] + c4.y;
      tg[mi][nt][2] = a[2] + (float)b4[2] + c4.z;
      tg[mi][nt][3] = a[3] + (float)b4[3] + c4.w;
    }
  }
  __syncthreads();

  // ---- GEMM2 (MFMA): acc = tg + wv1^T @ ev^T ----
  {
    const half8* wv1f8 = (const half8*)wv1f;
    const half8* evB   = (const half8*)evlds;   // index: e*17 + ks*4 + (lane>>4)
#pragma unroll
    for (int ks = 0; ks < 4; ++ks) {
      half8 bf0 = evB[(lane & 15)*17 + ks*4 + (lane >> 4)];
      half8 bf1 = evB[(16 + (lane & 15))*17 + ks*4 + (lane >> 4)];
#pragma unroll
      for (int mi = 0; mi < 2; ++mi) {
        half8 af = wv1f8[((2*wid + mi)*4 + ks)*64 + lane];
        tg[mi][0] = __builtin_amdgcn_mfma_f32_16x16x32_f16(af, bf0, tg[mi][0], 0, 0, 0);
        tg[mi][1] = __builtin_amdgcn_mfma_f32_16x16x32_f16(af, bf1, tg[mi][1], 0, 0, 0);
      }
    }
  }
  // gelu epilogue -> gt fp16 (disjoint from evlds; no barrier needed)
#pragma unroll
  for (int mi = 0; mi < 2; ++mi) {
    const int j0 = (2*wid + mi)*16 + ((lane >> 4) << 2);
#pragma unroll
    for (int nt = 0; nt < 2; ++nt) {
      const int e = nt*16 + (lane & 15);
      f32x4 a = tg[mi][nt];
      half4v gv;
#pragma unroll
      for (int jj = 0; jj < 4; ++jj) {
        float tval = a[jj];
        float u = 0.79788456080286536f*(tval + 0.044715f*tval*tval*tval);
        float ex = __expf(2.f*u);
        float th = 1.f - 2.f/(ex + 1.f);
        gv[jj] = (_Float16)(0.5f*tval*(1.f + th));
      }
      *(half4v*)(gt_h + e*136 + j0) = gv;
    }
  }
  __syncthreads();

  // ---- Phase F (MFMA): poL[32x12] = gt[32x128] @ wvoT^T[128x12], waves 0,1 ----
  if (wid < 2) {
    const int et = wid;
    f32x4 pacc = (f32x4)0.f;
    const half8* gA = (const half8*)gt_h;     // A-frag: row e = lane&15
    const half8* wB = (const half8*)wvoF;     // B-frag: col r = lane&15 (static)
#pragma unroll
    for (int ks = 0; ks < 4; ++ks) {
      half8 af = gA[(et*16 + (lane & 15))*17 + ks*4 + (lane >> 4)];
      half8 bf = wB[ks*64 + lane];
      pacc = __builtin_amdgcn_mfma_f32_16x16x32_f16(af, bf, pacc, 0, 0, 0);
    }
    const int r = lane & 15;
    if (r < 12) {
      const int e0 = et*16 + ((lane >> 4) << 2);
      poL[(e0 + 0)*12 + r] = pacc[0];
      poL[(e0 + 1)*12 + r] = pacc[1];
      poL[(e0 + 2)*12 + r] = pacc[2];
      poL[(e0 + 3)*12 + r] = pacc[3];
    }
  }
  __syncthreads();

  // ---- Phase G: softmax over K per head + combine ----
  if (tid < 128) {
    const int h = tid >> 5, e = tid & 31;
    float l = logits_s[e*4 + h];
    float mx = l;
#pragma unroll
    for (int off = 1; off < 32; off <<= 1) mx = fmaxf(mx, __shfl_xor(mx, off));
    float w = __expf(l - mx);
    float s = w;
#pragma unroll
    for (int off = 1; off < 32; off <<= 1) s += __shfl_xor(s, off);
    float att = w / s;
    float p0 = att * poL[e*12 + h*3 + 0];
    float p1 = att * poL[e*12 + h*3 + 1];
    float p2 = att * poL[e*12 + h*3 + 2];
#pragma unroll
    for (int off = 1; off < 32; off <<= 1) {
      p0 += __shfl_xor(p0, off);
      p1 += __shfl_xor(p1, off);
      p2 += __shfl_xor(p2, off);
    }
    if (e == 0) { hpart[h*4 + 0] = p0; hpart[h*4 + 1] = p1; hpart[h*4 + 2] = p2; }
  }
  __syncthreads();
  if (tid < 3) {
    out[(size_t)bn*3 + tid] = outconst[tid]
        + hpart[0*4 + tid] + hpart[1*4 + tid] + hpart[2*4 + tid] + hpart[3*4 + tid];
  }
}

extern "C" void kernel_launch(void* const* d_in, const int* in_sizes, int n_in,
                              void* d_out, int out_size, void* d_ws, size_t ws_size,
                              hipStream_t stream) {
  (void)in_sizes; (void)n_in; (void)out_size; (void)ws_size;
  const float* x    = (const float*)d_in[0];
  const float* p    = (const float*)d_in[1];
  const float* c    = (const float*)d_in[2];
  const float* g    = (const float*)d_in[3];
  const float* w1q  = (const float*)d_in[4];
  const float* w2q  = (const float*)d_in[5];
  const float* b2q  = (const float*)d_in[6];
  const float* w3q  = (const float*)d_in[7];
  const float* b3q  = (const float*)d_in[8];
  const float* w1v  = (const float*)d_in[9];
  const float* w2v  = (const float*)d_in[10];
  const float* b2v  = (const float*)d_in[11];
  const float* w3v  = (const float*)d_in[12];
  const float* b3v  = (const float*)d_in[13];
  const float* wk   = (const float*)d_in[14];
  const float* bk   = (const float*)d_in[15];
  const float* wvw  = (const float*)d_in[16];
  const float* bv   = (const float*)d_in[17];
  const float* wv1  = (const float*)d_in[18];
  const float* bv1  = (const float*)d_in[19];
  const float* wv2  = (const float*)d_in[20];
  const float* bv2  = (const float*)d_in[21];
  const float* wout = (const float*)d_in[22];
  const float* bout = (const float*)d_in[23];
  float* ws = (float*)d_ws;
  float* outp = (float*)d_out;

  hipLaunchKernelGGL(enf_preA, dim3(325), dim3(256), 0, stream,
                     w2q, w3q, b2q, b3q, w2v, w3v, b2v, b3v, wv1,
                     ws + OFF_U, ws + OFF_E, ws + OFF_CB, ws + OFF_BW,
                     ws + OFF_W2A, (_Float16*)(ws + OFF_WV1F));
  hipLaunchKernelGGL(enf_preBL, dim3(387), dim3(256), 0, stream,
                     c, wk, bk, wvw, bv, wv1,
                     ws + OFF_U, ws + OFF_E, ws + OFF_CB, ws + OFF_BW,
                     ws + OFF_W2A, b3v, bv1, wv2, wout, bv2, bout,
                     (_Float16*)(ws + OFF_W2F), ws + OFF_CGV,
                     (_Float16*)(ws + OFF_WVOF), ws + OFF_OUTC,
                     (_Float16*)(ws + OFF_KWH), ws + OFF_KB,
                     (_Float16*)(ws + OFF_VFH), (_Float16*)(ws + OFF_BASEH));
  hipLaunchKernelGGL(enf_main, dim3(B_*N_), dim3(256), 0, stream,
                     x, p, g, w1q, w1v,
                     (const _Float16*)(ws + OFF_W2F), (const _Float16*)(ws + OFF_WV1F),
                     ws + OFF_CGV, (const _Float16*)(ws + OFF_WVOF), ws + OFF_OUTC,
                     (const _Float16*)(ws + OFF_KWH), ws + OFF_KB,
                     (const _Float16*)(ws + OFF_VFH), (const _Float16*)(ws + OFF_BASEH),
                     outp);
}

// Round 16
// 196.148 us; speedup vs baseline: 1.8863x; 1.0010x over previous
//
#include <hip/hip_runtime.h>
#include <math.h>

#define B_ 4
#define N_ 2048
#define M_ 1024
#define K_ 32
#define HEADS_ 4
#define NH_ 128
#define PI_F 3.14159265358979323846f

typedef unsigned long long ull;
typedef __attribute__((ext_vector_type(8))) _Float16 half8;
typedef __attribute__((ext_vector_type(4))) _Float16 half4v;
typedef __attribute__((ext_vector_type(2))) _Float16 half2v;
typedef __attribute__((ext_vector_type(4))) float f32x4;

// workspace offsets (in floats)
#define OFF_CB     0         // 128
#define OFF_CGV    128       // 128
#define OFF_WVOF   256       // 1024 (2048 halfs: wvoT^T MFMA B-frags)
#define OFF_OUTC   1280      // 4
#define OFF_BW     1284      // 128
#define OFF_E      1412      // 256
#define OFF_KB     1668      // 16384
#define OFF_U      18052     // 33280
#define OFF_W2A    51332     // 33280
#define OFF_W2F    84612     // 20480 (40960 halfs)
#define OFF_WV1F   105092    // 8192 (16384 halfs)
#define OFF_BASEH  113284    // 262144 (B*M*128 halfs)
#define OFF_KWH    375428    // 1114112 (B*M*4*136 halfs)
#define OFF_VFH    1489540   // 262144 (B*M*128 halfs)
// total = 1751684 floats (~7.0 MB)

// W2f/wv1f fragment index for (k, n): [mt][ks][lane][i]
__device__ __forceinline__ int w2f_idx(int k, int n, int nks) {
  int mt = n >> 4, ks = k >> 5;
  int lane = (((k >> 3) & 3) << 4) | (n & 15);
  return (((mt*nks + ks)*64 + lane) << 3) + (k & 7);
}

// ---------- preA: U | E+cb+bW | W2A | wv1f  (no internal deps) ----------
__global__ __launch_bounds__(256) void enf_preA(
    const float* __restrict__ w2q, const float* __restrict__ w3q,
    const float* __restrict__ b2q, const float* __restrict__ b3q,
    const float* __restrict__ w2v, const float* __restrict__ w3v,
    const float* __restrict__ b2v, const float* __restrict__ b3v,
    const float* __restrict__ wv1,
    float* __restrict__ U, float* __restrict__ E, float* __restrict__ cb,
    float* __restrict__ bW, float* __restrict__ W2A,
    _Float16* __restrict__ wv1f) {
  const int blk = blockIdx.x, tid = threadIdx.x;
  if (blk < 130) {               // U[a][s] = w2q @ w3q
    int a = blk, s = tid;
    float acc = 0.f;
    for (int i = 0; i < 128; ++i) acc = fmaf(w2q[a*128 + i], w3q[i*256 + s], acc);
    U[a*256 + s] = acc;
  } else if (blk == 130) {       // E | cb | bW
    int s = tid;
    float acc = b3q[s];
    for (int j = 0; j < 128; ++j) acc = fmaf(b2q[j], w3q[j*256 + s], acc);
    E[s] = acc;
    if (tid < 128) {
      float a1 = 0.f, a2 = 0.f;
      for (int i = 0; i < 128; ++i) {
        a1 = fmaf(b2v[i], w3v[i*256 + tid], a1);
        a2 = fmaf(b2v[i], w3v[i*256 + 128 + tid], a2);
      }
      cb[tid] = a1 + b3v[tid];
      bW[tid] = a2;
    }
  } else if (blk < 261) {        // W2A[a][j] = w2v @ w3v (both halves)
    int a = blk - 131, j = tid;
    float acc = 0.f;
    for (int i = 0; i < 128; ++i) acc = fmaf(w2v[a*128 + i], w3v[i*256 + j], acc);
    W2A[a*256 + j] = acc;
  } else {                       // wv1f frags: [mt8][ks4][lane64][i8], blocks 261..324
    int idx = (blk - 261)*256 + tid;
    int i = idx & 7, lane = (idx >> 3) & 63;
    int rest = idx >> 9;
    int ks = rest & 3, mt = rest >> 2;
    int k = ks*32 + ((lane >> 4) << 3) + i;
    int j = mt*16 + (lane & 15);
    wv1f[idx] = (_Float16)wv1[k*128 + j];
  }
}

// ---------- preBL: latent tables (256 blk) | W2f (130 blk) | consts (1 blk) ----------
__global__ __launch_bounds__(256) void enf_preBL(
    const float* __restrict__ c, const float* __restrict__ wk,
    const float* __restrict__ bk, const float* __restrict__ wvw,
    const float* __restrict__ bv, const float* __restrict__ wv1,
    const float* __restrict__ U, const float* __restrict__ E,
    const float* __restrict__ cb, const float* __restrict__ bW,
    const float* __restrict__ W2A, const float* __restrict__ b3v,
    const float* __restrict__ bv1, const float* __restrict__ wv2,
    const float* __restrict__ wout, const float* __restrict__ bv2,
    const float* __restrict__ bout,
    _Float16* __restrict__ W2f, float* __restrict__ cgv,
    _Float16* __restrict__ wvoF, float* __restrict__ outconst,
    _Float16* __restrict__ kwh, float* __restrict__ kb,
    _Float16* __restrict__ vfh, _Float16* __restrict__ baseh) {
  const int blk = blockIdx.x, tid = threadIdx.x;
  __shared__ float cls[16][128];
  __shared__ float kfl[16][256];
  __shared__ float evs[16][128];
  if (blk < 256) {
    // ---- latent: 16 latents per block ----
    const int bm0 = blk * 16;
    for (int t = tid; t < 2048; t += 256) cls[t >> 7][t & 127] = c[(size_t)bm0*128 + t];
    __syncthreads();
    { // kf[i][s] = c@wk + bk  (thread owns column s)
      const int s = tid;
      float a[16];
#pragma unroll
      for (int i = 0; i < 16; ++i) a[i] = 0.f;
      for (int l = 0; l < 128; ++l) {
        float w = wk[l*256 + s];
#pragma unroll
        for (int i = 0; i < 16; ++i) a[i] = fmaf(cls[i][l], w, a[i]);
      }
      float bks = bk[s];
#pragma unroll
      for (int i = 0; i < 16; ++i) kfl[i][s] = a[i] + bks;
    }
    { // vf: 2 threads per col, 8 latents each
      const int col = tid & 127, i0 = (tid >> 7) * 8;
      float a[8];
#pragma unroll
      for (int i = 0; i < 8; ++i) a[i] = 0.f;
      for (int l = 0; l < 128; ++l) {
        float w = wvw[l*128 + col];
#pragma unroll
        for (int i = 0; i < 8; ++i) a[i] = fmaf(cls[i0 + i][l], w, a[i]);
      }
      float bvc = bv[col];
      float cbf = 1.f + cb[col];
#pragma unroll
      for (int i = 0; i < 8; ++i) {
        float v = a[i] + bvc;
        vfh[(size_t)(bm0 + i0 + i)*128 + col] = (_Float16)v;
        evs[i0 + i][col] = v*cbf;
      }
    }
    __syncthreads();
    { // base = evs @ wv1 (2 threads per col, 8 latents each)
      const int col = tid & 127, i0 = (tid >> 7) * 8;
      float a[8];
#pragma unroll
      for (int i = 0; i < 8; ++i) a[i] = 0.f;
      for (int l = 0; l < 128; ++l) {
        float w = wv1[l*128 + col];
#pragma unroll
        for (int i = 0; i < 8; ++i) a[i] = fmaf(evs[i0 + i][l], w, a[i]);
      }
#pragma unroll
      for (int i = 0; i < 8; ++i)
        baseh[(size_t)(bm0 + i0 + i)*128 + col] = (_Float16)a[i];
    }
    // kw[a,h] = sum_q U[a][h*64+q] * kf[h*64+q] ; kb via E
    for (int col = tid; col < 524; col += 256) {
      float a[16];
#pragma unroll
      for (int i = 0; i < 16; ++i) a[i] = 0.f;
      if (col < 520) {
        int h = col / 130, aa = col - h*130;
        const float* ur = U + aa*256 + h*64;
        for (int q = 0; q < 64; ++q) {
          float w = ur[q];
#pragma unroll
          for (int i = 0; i < 16; ++i) a[i] = fmaf(kfl[i][h*64 + q], w, a[i]);
        }
#pragma unroll
        for (int i = 0; i < 16; ++i)
          kwh[((size_t)(bm0 + i)*4 + h)*136 + aa] = (_Float16)a[i];
      } else {
        int h = col - 520;
        const float* er = E + h*64;
        for (int q = 0; q < 64; ++q) {
          float w = er[q];
#pragma unroll
          for (int i = 0; i < 16; ++i) a[i] = fmaf(kfl[i][h*64 + q], w, a[i]);
        }
#pragma unroll
        for (int i = 0; i < 16; ++i) kb[(size_t)(bm0 + i)*4 + h] = a[i];
      }
    }
  } else if (blk < 386) {
    // ---- W2f row a: left half copy, right half WB2 @ wv1 ----
    int a = blk - 256, j = tid;
    float acc;
    if (j < 128) {
      acc = W2A[a*256 + j];
    } else {
      int j2 = j - 128;
      acc = 0.f;
      for (int r = 0; r < 128; ++r) acc = fmaf(W2A[a*256 + 128 + r], wv1[r*128 + j2], acc);
    }
    W2f[w2f_idx(a, j, 5)] = (_Float16)acc;
  } else {
    // ---- consts: cgv | wvoF (frag layout) | outconst | W2f pad ----
    float* wvs = &cls[0][0];       // 12*128 fp32 scratch (block-local)
    if (tid < 128) {
      float a2 = 0.f;
      for (int r = 0; r < 128; ++r)
        a2 = fmaf(bW[r] + b3v[128 + r], wv1[r*128 + tid], a2);
      cgv[tid] = a2 + bv1[tid];
    }
    for (int o = tid; o < 1536; o += 256) {
      int r12 = o >> 7, i = o & 127;
      int h = r12 / 3, cc = r12 - h*3;
      float acc = 0.f;
      for (int k = 0; k < 128; ++k)
        acc = fmaf(wv2[i*512 + h*128 + k], wout[(h*128 + k)*3 + cc], acc);
      wvs[r12*128 + i] = acc;
    }
    for (int o = tid; o < 7680; o += 256) {
      int k = 130 + (o >> 8), n = o & 255;
      W2f[w2f_idx(k, n, 5)] = (_Float16)0.f;
    }
    if (tid < 3) {
      float acc = bout[tid];
      for (int r = 0; r < 512; ++r) acc = fmaf(bv2[r], wout[r*3 + tid], acc);
      outconst[tid] = acc;
    }
    __syncthreads();
    // wvoF[ks4][lane64][i8]: B[k][n] = wvoT[n][k] (n<12), 0 else
    for (int idx = tid; idx < 2048; idx += 256) {
      int i = idx & 7, lane = (idx >> 3) & 63, ks = idx >> 9;
      int k = ks*32 + ((lane >> 4) << 3) + i;
      int n = lane & 15;
      wvoF[idx] = (n < 12) ? (_Float16)wvs[n*128 + k] : (_Float16)0.f;
    }
  }
}

// sfv B-fragment position: [nt(2)][ks(5)][lane(64)][i(8)] halfs
__device__ __forceinline__ int fragpos(int k, int e) {
  return ((((e >> 4)*5 + (k >> 5))*64 + (((k >> 3) & 3) << 4) + (e & 15)) << 3) + (k & 7);
}

// ---------- main kernel: one block per (b,n), batch->XCD swizzled ----------
__global__ __launch_bounds__(256, 8) void enf_main(
    const float* __restrict__ x, const float* __restrict__ p,
    const float* __restrict__ g,
    const float* __restrict__ w1q, const float* __restrict__ w1v,
    const _Float16* __restrict__ w2f, const _Float16* __restrict__ wv1f,
    const float* __restrict__ cgv, const _Float16* __restrict__ wvoF,
    const float* __restrict__ outconst,
    const _Float16* __restrict__ kwh, const float* __restrict__ kb,
    const _Float16* __restrict__ vfh, const _Float16* __restrict__ baseh,
    float* __restrict__ out) {
  // batch->XCD affinity: XCD = wgid%8 serves exactly one batch (b = (bid&7)>>1)
  const int bid = blockIdx.x;
  const int bn = (((bid & 7) >> 1) << 11) | ((bid & 1) << 10) | (bid >> 3);
  const int b = bn >> 11;          // N = 2048
  const int tid = threadIdx.x;
  const int lane = tid & 63;
  const int wid = tid >> 6;

  __shared__ alignas(16) float S[4736];
  __shared__ int   selm[K_];
  __shared__ float seld[K_];
  __shared__ float gkv[K_];
  __shared__ float bi0[K_], bi1[K_];
  __shared__ float logits_s[K_*HEADS_];
  __shared__ float hpart[HEADS_*4];

  float* candd = S;
  int*   candm = (int*)(S + 128);
  half2v* sfq2 = (half2v*)S;                 // [32][68] half2 words (w = k>>1)
  _Float16* sfvB = (_Float16*)(S + 2176);    // 5120 halfs
  _Float16* evlds = (_Float16*)S;            // [32][136]
  _Float16* gt_h  = (_Float16*)S + 4352;     // [32][136]
  float* poL   = S;                          // [32][12]

  const float x0 = x[bn*2 + 0];
  const float x1 = x[bn*2 + 1];
  const float2* pb2 = (const float2*)(p + (size_t)b*M_*2);

  // ---- Phase A: per-wave top-32 via binary-search threshold on float bits ----
  unsigned db[4]; int mm[4];
#pragma unroll
  for (int s = 0; s < 4; ++s) {
    int m = wid*256 + s*64 + lane;
    float2 pv = pb2[m];
    float d0 = x0 - pv.x, d1 = x1 - pv.y;
    float d = __fadd_rn(__fmul_rn(d0, d0), __fmul_rn(d1, d1));
    db[s] = __float_as_uint(d);
    mm[s] = m;
  }
  unsigned xth = 0;
  for (int bit = 30; bit >= 0; --bit) {
    unsigned trial = xth | (1u << bit);
    int cnt = __popcll(__ballot(db[0] < trial)) + __popcll(__ballot(db[1] < trial))
            + __popcll(__ballot(db[2] < trial)) + __popcll(__ballot(db[3] < trial));
    if (cnt < 32) xth = trial;
  }
  {
    ull bl[4], be[4];
#pragma unroll
    for (int s = 0; s < 4; ++s) {
      bl[s] = __ballot(db[s] < xth);
      be[s] = __ballot(db[s] == xth);
    }
    int r = __popcll(bl[0]) + __popcll(bl[1]) + __popcll(bl[2]) + __popcll(bl[3]);
    const ull lmask = (1ull << lane) - 1ull;
    int pl = 0, pe = 0;
#pragma unroll
    for (int s = 0; s < 4; ++s) {
      if (db[s] < xth) {
        int pos = pl + __popcll(bl[s] & lmask);
        candd[wid*K_ + pos] = __uint_as_float(db[s]);
        candm[wid*K_ + pos] = mm[s];
      } else if (db[s] == xth) {
        int pos = r + pe + __popcll(be[s] & lmask);
        if (pos < K_) {
          candd[wid*K_ + pos] = __uint_as_float(db[s]);
          candm[wid*K_ + pos] = mm[s];
        }
      }
      pl += __popcll(bl[s]);
      pe += __popcll(be[s]);
    }
  }
  __syncthreads();
  // merge: linear rank scan (lists are NOT value-sorted!), float4-vectorized
  if (tid < 128) {
    float d = candd[tid];
    int m = candm[tid];
    int rank = 0;
    const float4* c4 = (const float4*)candd;
#pragma unroll 8
    for (int i = 0; i < 32; ++i) {
      float4 v = c4[i];
      int base = i*4;
      rank += (v.x < d || (v.x == d && base + 0 < tid)) ? 1 : 0;
      rank += (v.y < d || (v.y == d && base + 1 < tid)) ? 1 : 0;
      rank += (v.z < d || (v.z == d && base + 2 < tid)) ? 1 : 0;
      rank += (v.w < d || (v.w == d && base + 3 < tid)) ? 1 : 0;
    }
    if (rank < K_) {
      selm[rank] = m; seld[rank] = d;
      gkv[rank] = g[(size_t)b*M_ + m];
      float2 pv = pb2[m];
      bi0[rank] = x0 - pv.x;
      bi1[rank] = x1 - pv.y;
    }
  }
  __syncthreads();

  // ---- Phase B: sin features, sfq2 [e][68] half2 words, sfv fp16 B-frags ----
  if (tid < 32) {
    const int e = tid;
    half2v h;
    h[0] = (_Float16)__sinf(bi0[e]);
    h[1] = (_Float16)__sinf(bi1[e]);
    sfq2[e*68 + 0] = h;               // word 0: k=0,1
    sfvB[fragpos(0, e)] = h[0];
    sfvB[fragpos(1, e)] = h[1];
  }
  for (int t = tid; t < 960; t += 256) {      // zero-pad sfv frags k=130..159
    int k = 130 + (t >> 5), e = t & 31;
    sfvB[fragpos(k, e)] = (_Float16)0.f;
  }
  {
    const int e = tid & 31;
    const int jg = tid >> 5;           // 0..7
    const float s0 = PI_F*(bi0[e] + 1.f), s1 = PI_F*(bi1[e] + 1.f);
#pragma unroll
    for (int t4 = 0; t4 < 4; ++t4) {
      const int J = 2*jg + 16*t4;      // even, covers 0..62
      float eqa = s0*w1q[J]     + s1*w1q[64 + J];
      float eqb = s0*w1q[J + 1] + s1*w1q[64 + J + 1];
      float eva = s0*w1v[J]     + s1*w1v[64 + J];
      float evb = s0*w1v[J + 1] + s1*w1v[64 + J + 1];
      half2v hs, hc;
      hs[0] = (_Float16)__sinf(eqa); hs[1] = (_Float16)__sinf(eqb);
      hc[0] = (_Float16)__cosf(eqa); hc[1] = (_Float16)__cosf(eqb);
      sfq2[e*68 + 1 + (J >> 1)]  = hs;   // k = 2+J, 3+J
      sfq2[e*68 + 33 + (J >> 1)] = hc;   // k = 66+J, 67+J
      sfvB[fragpos(2 + J, e)]  = (_Float16)__sinf(eva);
      sfvB[fragpos(3 + J, e)]  = (_Float16)__sinf(evb);
      sfvB[fragpos(66 + J, e)] = (_Float16)__cosf(eva);
      sfvB[fragpos(67 + J, e)] = (_Float16)__cosf(evb);
    }
  }
  __syncthreads();

  // ---- Phase C: attention logits via b128 sfq reads + v_dot2 (waves 0,1) ----
  if (tid < 128) {
    const int e = tid >> 2, h = tid & 3;
    const int m = selm[e];
    const _Float16* kwrow = kwh + ((size_t)((b*M_ + m)*4 + h))*136;
    float accq = kb[(size_t)(b*M_ + m)*4 + h];
    const half8* kw8 = (const half8*)kwrow;
    const half8* sq8 = (const half8*)(sfq2 + e*68);
#pragma unroll 4
    for (int q8 = 0; q8 < 16; ++q8) {
      half8 kv = kw8[q8];
      half8 sv = sq8[q8];
      half2v k0; k0[0] = kv[0]; k0[1] = kv[1];
      half2v k1; k1[0] = kv[2]; k1[1] = kv[3];
      half2v k2; k2[0] = kv[4]; k2[1] = kv[5];
      half2v k3; k3[0] = kv[6]; k3[1] = kv[7];
      half2v s0; s0[0] = sv[0]; s0[1] = sv[1];
      half2v s1; s1[0] = sv[2]; s1[1] = sv[3];
      half2v s2; s2[0] = sv[4]; s2[1] = sv[5];
      half2v s3; s3[0] = sv[6]; s3[1] = sv[7];
      accq = __builtin_amdgcn_fdot2(s0, k0, accq, false);
      accq = __builtin_amdgcn_fdot2(s1, k1, accq, false);
      accq = __builtin_amdgcn_fdot2(s2, k2, accq, false);
      accq = __builtin_amdgcn_fdot2(s3, k3, accq, false);
    }
    {
      half2v kt = *(const half2v*)(kwrow + 128);
      accq = __builtin_amdgcn_fdot2(sfq2[e*68 + 64], kt, accq, false);
    }
    const float gk = gkv[e];
    logits_s[tid] = accq - seld[e]/(gk*gk);
  }

  // ---- GEMM1 (MFMA): C1T = W2^T @ sfv^T
  f32x4 acc1[4][2];
#pragma unroll
  for (int mi = 0; mi < 4; ++mi)
#pragma unroll
    for (int nt = 0; nt < 2; ++nt) acc1[mi][nt] = (f32x4)0.f;
  {
    const half8* w2f8  = (const half8*)w2f;
    const half8* sfvB8 = (const half8*)sfvB;
#pragma unroll
    for (int ks = 0; ks < 5; ++ks) {
      half8 bf0 = sfvB8[(0*5 + ks)*64 + lane];
      half8 bf1 = sfvB8[(1*5 + ks)*64 + lane];
#pragma unroll
      for (int mi = 0; mi < 4; ++mi) {
        const int mt = (mi < 2) ? (2*wid + mi) : (8 + 2*wid + (mi - 2));
        half8 af = w2f8[(mt*5 + ks)*64 + lane];
        acc1[mi][0] = __builtin_amdgcn_mfma_f32_16x16x32_f16(af, bf0, acc1[mi][0], 0, 0, 0);
        acc1[mi][1] = __builtin_amdgcn_mfma_f32_16x16x32_f16(af, bf1, acc1[mi][1], 0, 0, 0);
      }
    }
  }
  __syncthreads();   // sfq2 + sfvB dead

  // ---- epilogue: evec (mi 0,1) -> evlds fp16; gterm (mi 2,3) -> registers ----
  f32x4 tg[2][2];
#pragma unroll
  for (int mi = 0; mi < 2; ++mi) {
    const int j0 = (2*wid + mi)*16 + ((lane >> 4) << 2);
#pragma unroll
    for (int nt = 0; nt < 2; ++nt) {
      const int e = nt*16 + (lane & 15);
      const half4v v4 = *(const half4v*)(vfh + ((size_t)(b*M_ + selm[e]))*NH_ + j0);
      f32x4 a = acc1[mi][nt];
      half4v hv;
      hv[0] = (_Float16)((float)v4[0] * a[0]);
      hv[1] = (_Float16)((float)v4[1] * a[1]);
      hv[2] = (_Float16)((float)v4[2] * a[2]);
      hv[3] = (_Float16)((float)v4[3] * a[3]);
      *(half4v*)(evlds + e*136 + j0) = hv;
    }
  }
#pragma unroll
  for (int mi = 0; mi < 2; ++mi) {
    const int j0 = 32*wid + mi*16 + ((lane >> 4) << 2);
    const float4 c4 = *(const float4*)(cgv + j0);
#pragma unroll
    for (int nt = 0; nt < 2; ++nt) {
      const int e = nt*16 + (lane & 15);
      const half4v b4 = *(const half4v*)(baseh + ((size_t)(b*M_ + selm[e]))*NH_ + j0);
      f32x4 a = acc1[2 + mi][nt];
      tg[mi][nt][0] = a[0] + (float)b4[0] + c4.x;
      tg[mi][nt][1] = a[1] + (float)b4[1] + c4.y;
      tg[mi][nt][2] = a[2] + (float)b4[2] + c4.z;
      tg[mi][nt][3] = a[3] + (float)b4[3] + c4.w;
    }
  }
  __syncthreads();

  // ---- GEMM2 (MFMA): acc = tg + wv1^T @ ev^T ----
  {
    const half8* wv1f8 = (const half8*)wv1f;
    const half8* evB   = (const half8*)evlds;   // index: e*17 + ks*4 + (lane>>4)
#pragma unroll
    for (int ks = 0; ks < 4; ++ks) {
      half8 bf0 = evB[(lane & 15)*17 + ks*4 + (lane >> 4)];
      half8 bf1 = evB[(16 + (lane & 15))*17 + ks*4 + (lane >> 4)];
#pragma unroll
      for (int mi = 0; mi < 2; ++mi) {
        half8 af = wv1f8[((2*wid + mi)*4 + ks)*64 + lane];
        tg[mi][0] = __builtin_amdgcn_mfma_f32_16x16x32_f16(af, bf0, tg[mi][0], 0, 0, 0);
        tg[mi][1] = __builtin_amdgcn_mfma_f32_16x16x32_f16(af, bf1, tg[mi][1], 0, 0, 0);
      }
    }
  }
  // gelu epilogue -> gt fp16 (disjoint from evlds; no barrier needed)
#pragma unroll
  for (int mi = 0; mi < 2; ++mi) {
    const int j0 = (2*wid + mi)*16 + ((lane >> 4) << 2);
#pragma unroll
    for (int nt = 0; nt < 2; ++nt) {
      const int e = nt*16 + (lane & 15);
      f32x4 a = tg[mi][nt];
      half4v gv;
#pragma unroll
      for (int jj = 0; jj < 4; ++jj) {
        float tval = a[jj];
        float u = 0.79788456080286536f*(tval + 0.044715f*tval*tval*tval);
        float ex = __expf(2.f*u);
        float th = 1.f - 2.f/(ex + 1.f);
        gv[jj] = (_Float16)(0.5f*tval*(1.f + th));
      }
      *(half4v*)(gt_h + e*136 + j0) = gv;
    }
  }
  __syncthreads();

  // ---- Phase F (MFMA): poL[32x12] = gt[32x128] @ wvoT^T[128x12], waves 0,1 ----
  if (wid < 2) {
    const int et = wid;
    f32x4 pacc = (f32x4)0.f;
    const half8* gA = (const half8*)gt_h;     // A-frag: row e = lane&15
    const half8* wB = (const half8*)wvoF;     // B-frag: col r = lane&15 (static)
#pragma unroll
    for (int ks = 0; ks < 4; ++ks) {
      half8 af = gA[(et*16 + (lane & 15))*17 + ks*4 + (lane >> 4)];
      half8 bf = wB[ks*64 + lane];
      pacc = __builtin_amdgcn_mfma_f32_16x16x32_f16(af, bf, pacc, 0, 0, 0);
    }
    const int r = lane & 15;
    if (r < 12) {
      const int e0 = et*16 + ((lane >> 4) << 2);
      poL[(e0 + 0)*12 + r] = pacc[0];
      poL[(e0 + 1)*12 + r] = pacc[1];
      poL[(e0 + 2)*12 + r] = pacc[2];
      poL[(e0 + 3)*12 + r] = pacc[3];
    }
  }
  __syncthreads();

  // ---- Phase G: softmax over K per head + combine ----
  if (tid < 128) {
    const int h = tid >> 5, e = tid & 31;
    float l = logits_s[e*4 + h];
    float mx = l;
#pragma unroll
    for (int off = 1; off < 32; off <<= 1) mx = fmaxf(mx, __shfl_xor(mx, off));
    float w = __expf(l - mx);
    float s = w;
#pragma unroll
    for (int off = 1; off < 32; off <<= 1) s += __shfl_xor(s, off);
    float att = w / s;
    float p0 = att * poL[e*12 + h*3 + 0];
    float p1 = att * poL[e*12 + h*3 + 1];
    float p2 = att * poL[e*12 + h*3 + 2];
#pragma unroll
    for (int off = 1; off < 32; off <<= 1) {
      p0 += __shfl_xor(p0, off);
      p1 += __shfl_xor(p1, off);
      p2 += __shfl_xor(p2, off);
    }
    if (e == 0) { hpart[h*4 + 0] = p0; hpart[h*4 + 1] = p1; hpart[h*4 + 2] = p2; }
  }
  __syncthreads();
  if (tid < 3) {
    out[(size_t)bn*3 + tid] = outconst[tid]
        + hpart[0*4 + tid] + hpart[1*4 + tid] + hpart[2*4 + tid] + hpart[3*4 + tid];
  }
}

extern "C" void kernel_launch(void* const* d_in, const int* in_sizes, int n_in,
                              void* d_out, int out_size, void* d_ws, size_t ws_size,
                              hipStream_t stream) {
  (void)in_sizes; (void)n_in; (void)out_size; (void)ws_size;
  const float* x    = (const float*)d_in[0];
  const float* p    = (const float*)d_in[1];
  const float* c    = (const float*)d_in[2];
  const float* g    = (const float*)d_in[3];
  const float* w1q  = (const float*)d_in[4];
  const float* w2q  = (const float*)d_in[5];
  const float* b2q  = (const float*)d_in[6];
  const float* w3q  = (const float*)d_in[7];
  const float* b3q  = (const float*)d_in[8];
  const float* w1v  = (const float*)d_in[9];
  const float* w2v  = (const float*)d_in[10];
  const float* b2v  = (const float*)d_in[11];
  const float* w3v  = (const float*)d_in[12];
  const float* b3v  = (const float*)d_in[13];
  const float* wk   = (const float*)d_in[14];
  const float* bk   = (const float*)d_in[15];
  const float* wvw  = (const float*)d_in[16];
  const float* bv   = (const float*)d_in[17];
  const float* wv1  = (const float*)d_in[18];
  const float* bv1  = (const float*)d_in[19];
  const float* wv2  = (const float*)d_in[20];
  const float* bv2  = (const float*)d_in[21];
  const float* wout = (const float*)d_in[22];
  const float* bout = (const float*)d_in[23];
  float* ws = (float*)d_ws;
  float* outp = (float*)d_out;

  hipLaunchKernelGGL(enf_preA, dim3(325), dim3(256), 0, stream,
                     w2q, w3q, b2q, b3q, w2v, w3v, b2v, b3v, wv1,
                     ws + OFF_U, ws + OFF_E, ws + OFF_CB, ws + OFF_BW,
                     ws + OFF_W2A, (_Float16*)(ws + OFF_WV1F));
  hipLaunchKernelGGL(enf_preBL, dim3(387), dim3(256), 0, stream,
                     c, wk, bk, wvw, bv, wv1,
                     ws + OFF_U, ws + OFF_E, ws + OFF_CB, ws + OFF_BW,
                     ws + OFF_W2A, b3v, bv1, wv2, wout, bv2, bout,
                     (_Float16*)(ws + OFF_W2F), ws + OFF_CGV,
                     (_Float16*)(ws + OFF_WVOF), ws + OFF_OUTC,
                     (_Float16*)(ws + OFF_KWH), ws + OFF_KB,
                     (_Float16*)(ws + OFF_VFH), (_Float16*)(ws + OFF_BASEH));
  hipLaunchKernelGGL(enf_main, dim3(B_*N_), dim3(256), 0, stream,
                     x, p, g, w1q, w1v,
                     (const _Float16*)(ws + OFF_W2F), (const _Float16*)(ws + OFF_WV1F),
                     ws + OFF_CGV, (const _Float16*)(ws + OFF_WVOF), ws + OFF_OUTC,
                     (const _Float16*)(ws + OFF_KWH), ws + OFF_KB,
                     (const _Float16*)(ws + OFF_VFH), (const _Float16*)(ws + OFF_BASEH),
                     outp);
}